// Round 5
// baseline (392.517 us; speedup 1.0000x reference)
//
#include <hip/hip_runtime.h>
#include <stdint.h>

typedef __attribute__((ext_vector_type(8))) short bf8_t;   // 8 x bf16 (raw bits)
typedef __attribute__((ext_vector_type(4))) float f4_t;

#define DEV __device__ __forceinline__

constexpr int S_ = 1024;
constexpr int R_ = 1025;          // 2K+1
constexpr float SCALE_ = 0.07216878364870322f;  // 1/sqrt(3*64)

DEV float bf2f(unsigned short u) { union { unsigned int i; float f; } v; v.i = ((unsigned int)u) << 16; return v.f; }
DEV unsigned short f2bf(float f) {
  union { float fv; unsigned int i; } v; v.fv = f;
  unsigned int r = v.i + 0x7FFFu + ((v.i >> 16) & 1u);
  return (unsigned short)(r >> 16);
}

DEV void gll16(const unsigned short* g, unsigned short* l) {
  __builtin_amdgcn_global_load_lds(
      (const __attribute__((address_space(1))) unsigned int*)g,
      (__attribute__((address_space(3))) unsigned int*)l, 16, 0, 0);
}

// ---------------- fp32 -> bf16 bulk conversion (8 tensors, one launch) ----
struct CvtArgs { const float* src[8]; unsigned short* dst[8]; int nchunks[8]; };

__global__ __launch_bounds__(256) void cvt_kernel(CvtArgs a, int total) {
  int idx = blockIdx.x * 256 + threadIdx.x;
  int step = gridDim.x * 256;
  for (; idx < total; idx += step) {
    int c = idx, s = 0;
    while (c >= a.nchunks[s]) { c -= a.nchunks[s]; ++s; }
    float4 v = ((const float4*)a.src[s])[c];
    ushort4 o;
    o.x = f2bf(v.x); o.y = f2bf(v.y); o.z = f2bf(v.z); o.w = f2bf(v.w);
    ((ushort4*)a.dst[s])[c] = o;
  }
}

// ---------------- generic bf16 GEMM: C = A * B^T (+bias), epilogue modes --
enum { MQKV = 0, MVT = 1, MREL = 2, MCTX = 3, MOUT = 4 };

template <int BM, int BN, int MODE>
__global__ __launch_bounds__(256) void gemm_bt(
    const unsigned short* __restrict__ A, int lda, long abst,
    const unsigned short* __restrict__ B, int ldb, long bbst,
    void* __restrict__ C, const float* __restrict__ bias,
    int M, int N, int Kd)
{
  constexpr int WM = BM / 2, WN = BN / 2, FM = WM / 16, FN = WN / 16;
  __shared__ unsigned short At[BM][40];   // BK=32 + 8 pad
  __shared__ unsigned short Bt[BN][40];
  const int tid = threadIdx.x, lane = tid & 63, w = tid >> 6;
  const int wr = w >> 1, wc = w & 1;
  const int m0 = blockIdx.y * BM, n0 = blockIdx.x * BN;
  const int z = blockIdx.z;
  const unsigned short* Ab = A + (long)z * abst;
  const unsigned short* Bb = B + (long)z * bbst;

  f4_t acc[FM][FN];
#pragma unroll
  for (int i = 0; i < FM; ++i)
#pragma unroll
    for (int j = 0; j < FN; ++j) acc[i][j] = f4_t{0.f, 0.f, 0.f, 0.f};

  for (int k0 = 0; k0 < Kd; k0 += 32) {
    for (int c = tid; c < BM * 4; c += 256) {
      int row = c >> 2, c8 = (c & 3) * 8;
      int gm = m0 + row; if (gm > M - 1) gm = M - 1;
      *(int4*)&At[row][c8] = *(const int4*)(Ab + (long)gm * lda + k0 + c8);
    }
    for (int c = tid; c < BN * 4; c += 256) {
      int row = c >> 2, c8 = (c & 3) * 8;
      int gn = n0 + row; if (gn > N - 1) gn = N - 1;
      *(int4*)&Bt[row][c8] = *(const int4*)(Bb + (long)gn * ldb + k0 + c8);
    }
    __syncthreads();
    const int kk = (lane >> 4) * 8;
    bf8_t a[FM], b[FN];
#pragma unroll
    for (int fm = 0; fm < FM; ++fm) a[fm] = *(const bf8_t*)&At[wr * WM + fm * 16 + (lane & 15)][kk];
#pragma unroll
    for (int fn = 0; fn < FN; ++fn) b[fn] = *(const bf8_t*)&Bt[wc * WN + fn * 16 + (lane & 15)][kk];
#pragma unroll
    for (int fm = 0; fm < FM; ++fm)
#pragma unroll
      for (int fn = 0; fn < FN; ++fn)
        acc[fm][fn] = __builtin_amdgcn_mfma_f32_16x16x32_bf16(a[fm], b[fn], acc[fm][fn], 0, 0, 0);
    __syncthreads();
  }

#pragma unroll
  for (int fm = 0; fm < FM; ++fm)
#pragma unroll
    for (int fn = 0; fn < FN; ++fn)
#pragma unroll
      for (int r = 0; r < 4; ++r) {
        int row = wr * WM + fm * 16 + (lane >> 4) * 4 + r;
        int col = wc * WN + fn * 16 + (lane & 15);
        int m = m0 + row, n = n0 + col;
        if (m >= M || n >= N) continue;
        float v = acc[fm][fn][r];
        if (bias) v += bias[n];
        long off;
        if constexpr (MODE == MQKV)      off = (long)((m >> 10) * 12 + (n >> 6)) * 65536 + (m & 1023) * 64 + (n & 63);
        else if constexpr (MODE == MVT)  off = (long)((m >> 10) * 12 + (n >> 6)) * 65536 + (n & 63) * 1024 + (m & 1023);
        else if constexpr (MODE == MREL) off = (long)(n >> 6) * (R_ * 64) + (long)m * 64 + (n & 63);
        else if constexpr (MODE == MCTX) { int bb = z / 12, hh = z - bb * 12; off = (long)bb * 786432 + (long)m * 768 + hh * 64 + n; }
        else                             off = (long)m * 768 + n;
        if constexpr (MODE == MOUT) ((float*)C)[off] = v;
        else                        ((unsigned short*)C)[off] = f2bf(v);
      }
}

// ------- fused flash: cc + cp(on-chip) + pc(on-chip) + softmax + PV -------
// kr/qr window fragments software-pipelined into registers one iter ahead.
#define LOAD_FRAGS(JT, BCP, BPC) do {                                        \
    const int Dl_ = (JT) * 64 - i0;                                          \
    const int rbA_ = min(max(Dl_ - 63, -512), 512) + 512;                    \
    const int rbB_ = min(max(-Dl_ - 63, -512), 512) + 512;                   \
    _Pragma("unroll")                                                        \
    for (int ks_ = 0; ks_ < 2; ++ks_) {                                      \
      _Pragma("unroll")                                                      \
      for (int fn_ = 0; fn_ < 4; ++fn_) {                                    \
        int ra_ = rbA_ + nq * 64 + fn_ * 16 + li; if (ra_ > 1024) ra_ = 1024;\
        int rb_ = rbB_ + nq * 64 + fn_ * 16 + li; if (rb_ > 1024) rb_ = 1024;\
        BCP[ks_][fn_] = *(const bf8_t*)(krh + (long)ra_ * 64 + ks_ * 32 + g * 8); \
        BPC[ks_][fn_] = *(const bf8_t*)(qrh + (long)rb_ * 64 + ks_ * 32 + g * 8); \
      }                                                                      \
    }                                                                        \
  } while (0)

#define FLASH_BODY(JT, CUR, BCP_C, BPC_C, BCP_N, BPC_N) do {                 \
    const int j0 = (JT) * 64;                                                \
    const int Dl = j0 - i0;                                                  \
    const int rbase  = min(max(Dl - 63, -512), 512) + 512;                   \
    const int rbase2 = min(max(-Dl - 63, -512), 512) + 512;                  \
    asm volatile("s_waitcnt vmcnt(0)" ::: "memory");                         \
    __builtin_amdgcn_s_barrier();                                            \
    if ((JT) + 1 < 16) { stage((CUR) ^ 1, (JT) + 1); LOAD_FRAGS((JT) + 1, BCP_N, BPC_N); } \
    { /* Tcp = Qtile @ krWin^T (A hoisted, B pipelined regs) */              \
      f4_t acc[2][4];                                                        \
      _Pragma("unroll") for (int i = 0; i < 2; ++i)                          \
      _Pragma("unroll") for (int j = 0; j < 4; ++j) acc[i][j] = f4_t{0.f, 0.f, 0.f, 0.f}; \
      _Pragma("unroll") for (int ks = 0; ks < 2; ++ks)                       \
      _Pragma("unroll") for (int fm = 0; fm < 2; ++fm)                       \
      _Pragma("unroll") for (int fn = 0; fn < 4; ++fn)                       \
        acc[fm][fn] = __builtin_amdgcn_mfma_f32_16x16x32_bf16(q1[fm][ks], BCP_C[ks][fn], acc[fm][fn], 0, 0, 0); \
      _Pragma("unroll") for (int fm = 0; fm < 2; ++fm)                       \
      _Pragma("unroll") for (int fn = 0; fn < 4; ++fn)                       \
      _Pragma("unroll") for (int r = 0; r < 4; ++r)                          \
        TcpL[mh * 32 + fm * 16 + g * 4 + r][nq * 64 + fn * 16 + li] = f2bf(acc[fm][fn][r]); \
    }                                                                        \
    { /* Tpc = Ktile @ qrWin^T (A from swizzled LDS, B pipelined regs) */    \
      f4_t acc[2][4];                                                        \
      _Pragma("unroll") for (int i = 0; i < 2; ++i)                          \
      _Pragma("unroll") for (int j = 0; j < 4; ++j) acc[i][j] = f4_t{0.f, 0.f, 0.f, 0.f}; \
      _Pragma("unroll") for (int ks = 0; ks < 2; ++ks) {                     \
        bf8_t a[2];                                                          \
        _Pragma("unroll") for (int fm = 0; fm < 2; ++fm)                     \
          a[fm] = *chunk(Kt[CUR], mh * 32 + fm * 16 + li, ks * 4 + g);       \
        _Pragma("unroll") for (int fm = 0; fm < 2; ++fm)                     \
        _Pragma("unroll") for (int fn = 0; fn < 4; ++fn)                     \
          acc[fm][fn] = __builtin_amdgcn_mfma_f32_16x16x32_bf16(a[fm], BPC_C[ks][fn], acc[fm][fn], 0, 0, 0); \
      }                                                                      \
      _Pragma("unroll") for (int fm = 0; fm < 2; ++fm)                       \
      _Pragma("unroll") for (int fn = 0; fn < 4; ++fn)                       \
      _Pragma("unroll") for (int r = 0; r < 4; ++r)                          \
        Tpc[mh * 32 + fm * 16 + g * 4 + r][nq * 64 + fn * 16 + li] = f2bf(acc[fm][fn][r]); \
    }                                                                        \
    asm volatile("s_waitcnt lgkmcnt(0)" ::: "memory");                       \
    __builtin_amdgcn_s_barrier();                                            \
    f4_t s4[4];                                                              \
    _Pragma("unroll") for (int fn = 0; fn < 4; ++fn) s4[fn] = f4_t{0.f, 0.f, 0.f, 0.f}; \
    _Pragma("unroll") for (int ks = 0; ks < 2; ++ks) {                       \
      bf8_t b[4];                                                            \
      _Pragma("unroll") for (int fn = 0; fn < 4; ++fn)                       \
        b[fn] = *chunk(Kt[CUR], fn * 16 + li, ks * 4 + g);                   \
      _Pragma("unroll") for (int fn = 0; fn < 4; ++fn)                       \
        s4[fn] = __builtin_amdgcn_mfma_f32_16x16x32_bf16(q3[ks], b[fn], s4[fn], 0, 0, 0); \
    }                                                                        \
    float sc[4][4];                                                          \
    _Pragma("unroll") for (int fn = 0; fn < 4; ++fn)                         \
    _Pragma("unroll") for (int r = 0; r < 4; ++r) {                          \
      const int i_loc = w * 16 + g * 4 + r;                                  \
      const int j_loc = fn * 16 + li;                                        \
      const int d = (j0 + j_loc) - (i0 + i_loc);                             \
      int rc = d;   if (rc > 512) rc = 512;   if (rc < -512) rc = -512;   rc += 512; \
      int rc2 = -d; if (rc2 > 512) rc2 = 512; if (rc2 < -512) rc2 = -512; rc2 += 512; \
      float v = s4[fn][r] + bf2f(TcpL[i_loc][rc - rbase])                    \
                          + bf2f(Tpc[j_loc][rc2 - rbase2]);                  \
      sc[fn][r] = v * SCALE_;                                                \
    }                                                                        \
    float fac[4];                                                            \
    _Pragma("unroll") for (int r = 0; r < 4; ++r) {                          \
      float mx = fmaxf(fmaxf(sc[0][r], sc[1][r]), fmaxf(sc[2][r], sc[3][r]));\
      _Pragma("unroll") for (int off = 1; off < 16; off <<= 1) mx = fmaxf(mx, __shfl_xor(mx, off)); \
      float mnew = fmaxf(m_r[r], mx);                                        \
      fac[r] = __expf(m_r[r] - mnew);                                        \
      float rs = 0.f;                                                        \
      _Pragma("unroll") for (int fn = 0; fn < 4; ++fn) { sc[fn][r] = __expf(sc[fn][r] - mnew); rs += sc[fn][r]; } \
      _Pragma("unroll") for (int off = 1; off < 16; off <<= 1) rs += __shfl_xor(rs, off); \
      l_r[r] = l_r[r] * fac[r] + rs;                                         \
      m_r[r] = mnew;                                                         \
    }                                                                        \
    _Pragma("unroll") for (int fn = 0; fn < 4; ++fn)                         \
    _Pragma("unroll") for (int r = 0; r < 4; ++r) acc_o[fn][r] *= fac[r];    \
    _Pragma("unroll") for (int fn = 0; fn < 4; ++fn)                         \
    _Pragma("unroll") for (int r = 0; r < 4; ++r) {                          \
      const int row = w * 16 + g * 4 + r;                                    \
      int byte = row * 128 + (fn * 16 + li) * 2;                             \
      byte ^= (row & 7) << 4;                                                \
      *(unsigned short*)((char*)Pl + byte) = f2bf(sc[fn][r]);                \
    }                                                                        \
    _Pragma("unroll") for (int ks = 0; ks < 2; ++ks) {                       \
      const int arow = w * 16 + li;                                          \
      int abyte = arow * 128 + ks * 64 + g * 16;                             \
      abyte ^= (arow & 7) << 4;                                              \
      bf8_t a = *(const bf8_t*)((const char*)Pl + abyte);                    \
      bf8_t b[4];                                                            \
      _Pragma("unroll") for (int fn2 = 0; fn2 < 4; ++fn2)                    \
        b[fn2] = *chunk(Vl[CUR], fn2 * 16 + li, ks * 4 + g);                 \
      _Pragma("unroll") for (int fn2 = 0; fn2 < 4; ++fn2)                    \
        acc_o[fn2] = __builtin_amdgcn_mfma_f32_16x16x32_bf16(a, b[fn2], acc_o[fn2], 0, 0, 0); \
    }                                                                        \
  } while (0)

__global__ __launch_bounds__(256) void flash_kernel(
    const unsigned short* __restrict__ Q, const unsigned short* __restrict__ Kc,
    const unsigned short* __restrict__ kr, const unsigned short* __restrict__ qr,
    const unsigned short* __restrict__ Vt, unsigned short* __restrict__ ctx)
{
  // bijective XCD swizzle: each XCD owns 6 whole bh (all 16 i-tiles together)
  const int flat = blockIdx.x;
  const int logical = (flat & 7) * 96 + (flat >> 3);
  const int bh = logical >> 4, h = bh % 12, bb = bh / 12;
  const int i0 = (logical & 15) * 64;
  const int tid = threadIdx.x, lane = tid & 63, w = tid >> 6;
  const int g = lane >> 4, li = lane & 15;
  const unsigned short* Qb  = Q  + (long)bh * (S_ * 64);
  const unsigned short* Kb  = Kc + (long)bh * (S_ * 64);
  const unsigned short* Vb  = Vt + (long)bh * (S_ * 64);   // [64 d][1024 s]
  const unsigned short* krh = kr + (long)h * (R_ * 64);
  const unsigned short* qrh = qr + (long)h * (R_ * 64);

  __shared__ unsigned short Kt[2][4096];   // [buf] 64 rows x 64el, XOR-swizzled chunks
  __shared__ unsigned short Vl[2][4096];
  __shared__ unsigned short TcpL[64][136];
  __shared__ unsigned short Tpc[64][136];
  __shared__ unsigned short Pl[4096];      // per-wave private P rows, XOR-swizzled

  const int mh = w & 1, nq = w >> 1;

  // stage K-tile + V-tile for tile jt into buffer buf (source-preswizzled)
  const int sr0 = w * 8 + (lane >> 3);
  const int scc = (lane & 7) ^ (sr0 & 7);      // same for sr0 and sr0+32
  auto stage = [&](int buf, int jt) {
    const int j0n = jt * 64;
    gll16(Kb + (long)(j0n + sr0) * 64 + scc * 8,      &Kt[buf][w * 512 + lane * 8]);
    gll16(Kb + (long)(j0n + sr0 + 32) * 64 + scc * 8, &Kt[buf][w * 512 + 2048 + lane * 8]);
    gll16(Vb + (long)sr0 * 1024 + j0n + scc * 8,        &Vl[buf][w * 512 + lane * 8]);
    gll16(Vb + (long)(sr0 + 32) * 1024 + j0n + scc * 8, &Vl[buf][w * 512 + 2048 + lane * 8]);
  };
  auto chunk = [&](const unsigned short* base, int row, int ck) -> const bf8_t* {
    return (const bf8_t*)((const char*)base + row * 128 + ((ck ^ (row & 7)) << 4));
  };

  // hoisted Q fragments
  bf8_t q1[2][2];  // Tcp A: rows i0 + mh*32 + fm*16 + li
#pragma unroll
  for (int fm = 0; fm < 2; ++fm)
#pragma unroll
    for (int ks = 0; ks < 2; ++ks)
      q1[fm][ks] = *(const bf8_t*)(Qb + (long)(i0 + mh * 32 + fm * 16 + li) * 64 + ks * 32 + g * 8);
  bf8_t q3[2];     // cc A: rows i0 + w*16 + li
#pragma unroll
  for (int ks = 0; ks < 2; ++ks)
    q3[ks] = *(const bf8_t*)(Qb + (long)(i0 + w * 16 + li) * 64 + ks * 32 + g * 8);

  float m_r[4], l_r[4];
  f4_t acc_o[4];
#pragma unroll
  for (int r = 0; r < 4; ++r) { m_r[r] = -1e30f; l_r[r] = 0.f; }
#pragma unroll
  for (int fn = 0; fn < 4; ++fn) acc_o[fn] = f4_t{0.f, 0.f, 0.f, 0.f};

  // double-buffered kr/qr fragment registers (named, no runtime indexing)
  bf8_t bcpA[2][4], bpcA[2][4], bcpB[2][4], bpcB[2][4];
  LOAD_FRAGS(0, bcpA, bpcA);
  stage(0, 0);

  for (int jt0 = 0; jt0 < 16; jt0 += 2) {
    FLASH_BODY(jt0,     0, bcpA, bpcA, bcpB, bpcB);
    FLASH_BODY(jt0 + 1, 1, bcpB, bpcB, bcpA, bpcA);
  }

  // epilogue: normalize, write ctx [B*S, E] bf16
#pragma unroll
  for (int fn2 = 0; fn2 < 4; ++fn2)
#pragma unroll
    for (int r = 0; r < 4; ++r) {
      const int row = i0 + w * 16 + g * 4 + r;
      const int d = fn2 * 16 + li;
      float v = acc_o[fn2][r] / l_r[r];
      ctx[((long)bb * 1024 + row) * 768 + h * 64 + d] = f2bf(v);
    }
}

// ---------------- host launch ---------------------------------------------
extern "C" void kernel_launch(void* const* d_in, const int* in_sizes, int n_in,
                              void* d_out, int out_size, void* d_ws, size_t ws_size,
                              hipStream_t stream)
{
  const float* x   = (const float*)d_in[0];
  const float* Wq  = (const float*)d_in[1];
  const float* bq  = (const float*)d_in[2];
  const float* Wk  = (const float*)d_in[3];
  const float* bk  = (const float*)d_in[4];
  const float* Wv  = (const float*)d_in[5];
  const float* bv  = (const float*)d_in[6];
  const float* Wpq = (const float*)d_in[7];
  const float* bpq = (const float*)d_in[8];
  const float* Wpk = (const float*)d_in[9];
  const float* bpk = (const float*)d_in[10];
  const float* rel = (const float*)d_in[11];
  const float* Wo  = (const float*)d_in[12];
  const float* bo  = (const float*)d_in[13];

  char* ws = (char*)d_ws;
  auto alloc = [&](size_t bytes) { char* p = ws; ws += (bytes + 255) & ~(size_t)255; return p; };
  unsigned short* xb   = (unsigned short*)alloc((size_t)4096 * 768 * 2);
  unsigned short* Wqb  = (unsigned short*)alloc((size_t)768 * 768 * 2);
  unsigned short* Wkb  = (unsigned short*)alloc((size_t)768 * 768 * 2);
  unsigned short* Wvb  = (unsigned short*)alloc((size_t)768 * 768 * 2);
  unsigned short* Wpqb = (unsigned short*)alloc((size_t)768 * 768 * 2);
  unsigned short* Wpkb = (unsigned short*)alloc((size_t)768 * 768 * 2);
  unsigned short* Wob  = (unsigned short*)alloc((size_t)768 * 768 * 2);
  unsigned short* relb = (unsigned short*)alloc((size_t)1025 * 768 * 2);
  unsigned short* Qb   = (unsigned short*)alloc((size_t)48 * 1024 * 64 * 2);  // [B,H,S,D]
  unsigned short* Kb   = (unsigned short*)alloc((size_t)48 * 1024 * 64 * 2);  // [B,H,S,D]
  unsigned short* Vt   = (unsigned short*)alloc((size_t)48 * 64 * 1024 * 2);  // [B,H,D,S]
  unsigned short* qrb  = (unsigned short*)alloc((size_t)12 * 1025 * 64 * 2);  // [H,R,D]
  unsigned short* krb  = (unsigned short*)alloc((size_t)12 * 1025 * 64 * 2);
  unsigned short* ctx  = (unsigned short*)alloc((size_t)4096 * 768 * 2);      // [B*S, E]

  CvtArgs ca;
  const float* srcs[8] = {x, Wq, Wk, Wv, Wpq, Wpk, Wo, rel};
  unsigned short* dsts[8] = {xb, Wqb, Wkb, Wvb, Wpqb, Wpkb, Wob, relb};
  const int nch[8] = {786432, 147456, 147456, 147456, 147456, 147456, 147456, 196800};
  int total = 0;
  for (int i = 0; i < 8; ++i) { ca.src[i] = srcs[i]; ca.dst[i] = dsts[i]; ca.nchunks[i] = nch[i]; total += nch[i]; }
  cvt_kernel<<<dim3(2048), dim3(256), 0, stream>>>(ca, total);

  dim3 blk(256);
  // content projections: [4096,768] x [768,768]^T
  gemm_bt<64, 128, MQKV><<<dim3(6, 64, 1), blk, 0, stream>>>(xb, 768, 0, Wqb, 768, 0, Qb, bq, 4096, 768, 768);
  gemm_bt<64, 128, MQKV><<<dim3(6, 64, 1), blk, 0, stream>>>(xb, 768, 0, Wkb, 768, 0, Kb, bk, 4096, 768, 768);
  gemm_bt<64, 128, MVT ><<<dim3(6, 64, 1), blk, 0, stream>>>(xb, 768, 0, Wvb, 768, 0, Vt, bv, 4096, 768, 768);
  // positional projections: [1025,768] x [768,768]^T
  gemm_bt<64, 128, MREL><<<dim3(6, 17, 1), blk, 0, stream>>>(relb, 768, 0, Wpqb, 768, 0, qrb, bpq, 1025, 768, 768);
  gemm_bt<64, 128, MREL><<<dim3(6, 17, 1), blk, 0, stream>>>(relb, 768, 0, Wpkb, 768, 0, krb, bpk, 1025, 768, 768);
  // fused scores(cc+cp+pc) + softmax + PV  (768 blocks, XCD-swizzled)
  flash_kernel<<<dim3(768), blk, 0, stream>>>(Qb, Kb, krb, qrb, Vt, ctx);
  // output projection: [4096,768] x [768,768]^T -> fp32 d_out
  gemm_bt<64, 128, MOUT><<<dim3(6, 64, 1), blk, 0, stream>>>(ctx, 768, 0, Wob, 768, 0, d_out, bo, 4096, 768, 768);

  (void)in_sizes; (void)n_in; (void)out_size; (void)ws_size;
}

// Round 6
// 310.342 us; speedup vs baseline: 1.2648x; 1.2648x over previous
//
#include <hip/hip_runtime.h>
#include <stdint.h>

typedef __attribute__((ext_vector_type(8))) short bf8_t;   // 8 x bf16 (raw bits)
typedef __attribute__((ext_vector_type(4))) float f4_t;

#define DEV __device__ __forceinline__

constexpr int S_ = 1024;
constexpr int R_ = 1025;          // 2K+1
constexpr float SCALE_ = 0.07216878364870322f;  // 1/sqrt(3*64)

DEV float bf2f(unsigned short u) { union { unsigned int i; float f; } v; v.i = ((unsigned int)u) << 16; return v.f; }
DEV unsigned short f2bf(float f) {
  union { float fv; unsigned int i; } v; v.fv = f;
  unsigned int r = v.i + 0x7FFFu + ((v.i >> 16) & 1u);
  return (unsigned short)(r >> 16);
}

DEV void gll16(const unsigned short* g, unsigned short* l) {
  __builtin_amdgcn_global_load_lds(
      (const __attribute__((address_space(1))) unsigned int*)g,
      (__attribute__((address_space(3))) unsigned int*)l, 16, 0, 0);
}

// ---------------- fp32 -> bf16 bulk conversion (8 tensors, one launch) ----
struct CvtArgs { const float* src[8]; unsigned short* dst[8]; int nchunks[8]; };

__global__ __launch_bounds__(256) void cvt_kernel(CvtArgs a, int total) {
  int idx = blockIdx.x * 256 + threadIdx.x;
  int step = gridDim.x * 256;
  for (; idx < total; idx += step) {
    int c = idx, s = 0;
    while (c >= a.nchunks[s]) { c -= a.nchunks[s]; ++s; }
    float4 v = ((const float4*)a.src[s])[c];
    ushort4 o;
    o.x = f2bf(v.x); o.y = f2bf(v.y); o.z = f2bf(v.z); o.w = f2bf(v.w);
    ((ushort4*)a.dst[s])[c] = o;
  }
}

// ---- generic bf16 GEMM: C = A * B^T (+bias), gll16 staging, 64x128 tile --
enum { MQKV = 0, MVT = 1, MREL = 2, MCTX = 3, MOUT = 4 };

template <int MODE>
__global__ __launch_bounds__(256) void gemm_bt(
    const unsigned short* __restrict__ A, int lda, long abst,
    const unsigned short* __restrict__ B, int ldb, long bbst,
    void* __restrict__ C, const float* __restrict__ bias,
    int M, int N, int Kd)
{
  // BM=64, BN=128, BK=32 shorts (64B rows = 4 chunks of 16B)
  __shared__ unsigned short At[64 * 32];    // 4KB, chunk-swizzled: chunk ^= (row>>1)&3
  __shared__ unsigned short Bt[128 * 32];   // 8KB
  const int tid = threadIdx.x, lane = tid & 63, w = tid >> 6;
  const int li = lane & 15, g = lane >> 4;
  const int wr = w >> 1, wc = w & 1;
  const int sk = (li >> 1) & 3;             // read-side swizzle key
  const int m0 = blockIdx.y * 64, n0 = blockIdx.x * 128;
  const int z = blockIdx.z;
  const unsigned short* Ab = A + (long)z * abst;
  const unsigned short* Bb = B + (long)z * bbst;

  // staging: chunk index c -> row=c>>2, phys chunk p=c&3, logical l = p ^ ((row>>1)&3)
  const int arow = tid >> 2, ap = tid & 3;
  const int al = ap ^ ((arow >> 1) & 3);
  const long asrc = (long)min(m0 + arow, M - 1) * lda + al * 8;
  const int brow0 = tid >> 2, bl0 = (tid & 3) ^ ((brow0 >> 1) & 3);
  const int brow1 = (tid + 256) >> 2, bl1 = (tid & 3) ^ ((brow1 >> 1) & 3);
  const long bsrc0 = (long)min(n0 + brow0, N - 1) * ldb + bl0 * 8;
  const long bsrc1 = (long)min(n0 + brow1, N - 1) * ldb + bl1 * 8;

  f4_t acc[2][4];
#pragma unroll
  for (int i = 0; i < 2; ++i)
#pragma unroll
    for (int j = 0; j < 4; ++j) acc[i][j] = f4_t{0.f, 0.f, 0.f, 0.f};

  for (int k0 = 0; k0 < Kd; k0 += 32) {
    gll16(Ab + asrc + k0,  At + w * 512 + lane * 8);
    gll16(Bb + bsrc0 + k0, Bt + w * 512 + lane * 8);
    gll16(Bb + bsrc1 + k0, Bt + 2048 + w * 512 + lane * 8);
    asm volatile("s_waitcnt vmcnt(0)" ::: "memory");
    __syncthreads();

    bf8_t a[2], b[4];
#pragma unroll
    for (int fm = 0; fm < 2; ++fm) {
      int row = wr * 32 + fm * 16 + li;
      a[fm] = *(const bf8_t*)(At + row * 32 + (g ^ sk) * 8);
    }
#pragma unroll
    for (int fn = 0; fn < 4; ++fn) {
      int row = wc * 64 + fn * 16 + li;
      b[fn] = *(const bf8_t*)(Bt + row * 32 + (g ^ sk) * 8);
    }
#pragma unroll
    for (int fm = 0; fm < 2; ++fm)
#pragma unroll
      for (int fn = 0; fn < 4; ++fn)
        acc[fm][fn] = __builtin_amdgcn_mfma_f32_16x16x32_bf16(a[fm], b[fn], acc[fm][fn], 0, 0, 0);
    __syncthreads();
  }

#pragma unroll
  for (int fm = 0; fm < 2; ++fm)
#pragma unroll
    for (int fn = 0; fn < 4; ++fn)
#pragma unroll
      for (int r = 0; r < 4; ++r) {
        int row = wr * 32 + fm * 16 + (lane >> 4) * 4 + r;
        int col = wc * 64 + fn * 16 + li;
        int m = m0 + row, n = n0 + col;
        if (m >= M || n >= N) continue;
        float v = acc[fm][fn][r];
        if (bias) v += bias[n];
        long off;
        if constexpr (MODE == MQKV)      off = (long)((m >> 10) * 12 + (n >> 6)) * 65536 + (m & 1023) * 64 + (n & 63);
        else if constexpr (MODE == MVT)  off = (long)((m >> 10) * 12 + (n >> 6)) * 65536 + (n & 63) * 1024 + (m & 1023);
        else if constexpr (MODE == MREL) off = (long)(n >> 6) * (R_ * 64) + (long)m * 64 + (n & 63);
        else if constexpr (MODE == MCTX) { int bb = z / 12, hh = z - bb * 12; off = (long)bb * 786432 + (long)m * 768 + hh * 64 + n; }
        else                             off = (long)m * 768 + n;
        if constexpr (MODE == MOUT) ((float*)C)[off] = v;
        else                        ((unsigned short*)C)[off] = f2bf(v);
      }
}

// ------- fused flash: cc + cp(on-chip) + pc(on-chip) + softmax + PV -------
__global__ __launch_bounds__(256) void flash_kernel(
    const unsigned short* __restrict__ Q, const unsigned short* __restrict__ Kc,
    const unsigned short* __restrict__ kr, const unsigned short* __restrict__ qr,
    const unsigned short* __restrict__ Vt, unsigned short* __restrict__ ctx)
{
  // bijective XCD swizzle: each XCD owns 6 whole bh (all 16 i-tiles together)
  const int flat = blockIdx.x;
  const int logical = (flat & 7) * 96 + (flat >> 3);
  const int bh = logical >> 4, h = bh % 12, bb = bh / 12;
  const int i0 = (logical & 15) * 64;
  const int tid = threadIdx.x, lane = tid & 63, w = tid >> 6;
  const int g = lane >> 4, li = lane & 15;
  const unsigned short* Qb  = Q  + (long)bh * (S_ * 64);
  const unsigned short* Kb  = Kc + (long)bh * (S_ * 64);
  const unsigned short* Vb  = Vt + (long)bh * (S_ * 64);   // [64 d][1024 s]
  const unsigned short* krh = kr + (long)h * (R_ * 64);
  const unsigned short* qrh = qr + (long)h * (R_ * 64);

  __shared__ unsigned short Kt[2][4096];   // [buf] 64 rows x 64el, XOR-swizzled chunks
  __shared__ unsigned short Vl[2][4096];
  __shared__ unsigned short TcpL[64][136];
  __shared__ unsigned short Tpc[64][136];
  __shared__ unsigned short Pl[4096];      // per-wave private P rows, XOR-swizzled

  const int mh = w & 1, nq = w >> 1;

  // stage K-tile + V-tile for tile jt into buffer buf (source-preswizzled)
  const int sr0 = w * 8 + (lane >> 3);
  const int scc = (lane & 7) ^ (sr0 & 7);      // same for sr0 and sr0+32
  auto stage = [&](int buf, int jt) {
    const int j0n = jt * 64;
    gll16(Kb + (long)(j0n + sr0) * 64 + scc * 8,      &Kt[buf][w * 512 + lane * 8]);
    gll16(Kb + (long)(j0n + sr0 + 32) * 64 + scc * 8, &Kt[buf][w * 512 + 2048 + lane * 8]);
    gll16(Vb + (long)sr0 * 1024 + j0n + scc * 8,        &Vl[buf][w * 512 + lane * 8]);
    gll16(Vb + (long)(sr0 + 32) * 1024 + j0n + scc * 8, &Vl[buf][w * 512 + 2048 + lane * 8]);
  };
  auto chunk = [&](const unsigned short* base, int row, int ck) -> const bf8_t* {
    return (const bf8_t*)((const char*)base + row * 128 + ((ck ^ (row & 7)) << 4));
  };

  // hoisted Q fragments
  bf8_t q1[2][2];  // Tcp A: rows i0 + mh*32 + fm*16 + li
#pragma unroll
  for (int fm = 0; fm < 2; ++fm)
#pragma unroll
    for (int ks = 0; ks < 2; ++ks)
      q1[fm][ks] = *(const bf8_t*)(Qb + (long)(i0 + mh * 32 + fm * 16 + li) * 64 + ks * 32 + g * 8);
  bf8_t q3[2];     // cc A: rows i0 + w*16 + li
#pragma unroll
  for (int ks = 0; ks < 2; ++ks)
    q3[ks] = *(const bf8_t*)(Qb + (long)(i0 + w * 16 + li) * 64 + ks * 32 + g * 8);

  float m_r[4], l_r[4];
  f4_t acc_o[4];
#pragma unroll
  for (int r = 0; r < 4; ++r) { m_r[r] = -1e30f; l_r[r] = 0.f; }
#pragma unroll
  for (int fn = 0; fn < 4; ++fn) acc_o[fn] = f4_t{0.f, 0.f, 0.f, 0.f};

  stage(0, 0);

  for (int jt = 0; jt < 16; ++jt) {
    const int cur = jt & 1;
    const int j0 = jt * 64;
    const int Dl = j0 - i0;
    const int rbase  = min(max(Dl - 63, -512), 512) + 512;
    const int rbase2 = min(max(-Dl - 63, -512), 512) + 512;

    asm volatile("s_waitcnt vmcnt(0)" ::: "memory");
    __builtin_amdgcn_s_barrier();
    if (jt + 1 < 16) stage(cur ^ 1, jt + 1);

    { // Tcp = Qtile(64x64) @ krWin(128x64)^T  (A hoisted, B global/L2)
      f4_t acc[2][4];
#pragma unroll
      for (int i = 0; i < 2; ++i)
#pragma unroll
        for (int j = 0; j < 4; ++j) acc[i][j] = f4_t{0.f, 0.f, 0.f, 0.f};
#pragma unroll
      for (int ks = 0; ks < 2; ++ks) {
        bf8_t b[4];
#pragma unroll
        for (int fn = 0; fn < 4; ++fn) {
          int krow = rbase + nq * 64 + fn * 16 + li;
          if (krow > 1024) krow = 1024;
          b[fn] = *(const bf8_t*)(krh + (long)krow * 64 + ks * 32 + g * 8);
        }
#pragma unroll
        for (int fm = 0; fm < 2; ++fm)
#pragma unroll
          for (int fn = 0; fn < 4; ++fn)
            acc[fm][fn] = __builtin_amdgcn_mfma_f32_16x16x32_bf16(q1[fm][ks], b[fn], acc[fm][fn], 0, 0, 0);
      }
#pragma unroll
      for (int fm = 0; fm < 2; ++fm)
#pragma unroll
        for (int fn = 0; fn < 4; ++fn)
#pragma unroll
          for (int r = 0; r < 4; ++r)
            TcpL[mh * 32 + fm * 16 + g * 4 + r][nq * 64 + fn * 16 + li] = f2bf(acc[fm][fn][r]);
    }

    { // Tpc = Ktile(64x64) @ qrWin(128x64)^T  (A from swizzled LDS, B global/L2)
      f4_t acc[2][4];
#pragma unroll
      for (int i = 0; i < 2; ++i)
#pragma unroll
        for (int j = 0; j < 4; ++j) acc[i][j] = f4_t{0.f, 0.f, 0.f, 0.f};
#pragma unroll
      for (int ks = 0; ks < 2; ++ks) {
        bf8_t a[2], b[4];
#pragma unroll
        for (int fm = 0; fm < 2; ++fm)
          a[fm] = *chunk(Kt[cur], mh * 32 + fm * 16 + li, ks * 4 + g);
#pragma unroll
        for (int fn = 0; fn < 4; ++fn) {
          int krow = rbase2 + nq * 64 + fn * 16 + li;
          if (krow > 1024) krow = 1024;
          b[fn] = *(const bf8_t*)(qrh + (long)krow * 64 + ks * 32 + g * 8);
        }
#pragma unroll
        for (int fm = 0; fm < 2; ++fm)
#pragma unroll
          for (int fn = 0; fn < 4; ++fn)
            acc[fm][fn] = __builtin_amdgcn_mfma_f32_16x16x32_bf16(a[fm], b[fn], acc[fm][fn], 0, 0, 0);
      }
#pragma unroll
      for (int fm = 0; fm < 2; ++fm)
#pragma unroll
        for (int fn = 0; fn < 4; ++fn)
#pragma unroll
          for (int r = 0; r < 4; ++r)
            Tpc[mh * 32 + fm * 16 + g * 4 + r][nq * 64 + fn * 16 + li] = f2bf(acc[fm][fn][r]);
    }

    asm volatile("s_waitcnt lgkmcnt(0)" ::: "memory");
    __builtin_amdgcn_s_barrier();

    // cc MFMA — wave w: rows [w*16, w*16+16), all 64 cols, K from swizzled LDS
    f4_t s4[4];
#pragma unroll
    for (int fn = 0; fn < 4; ++fn) s4[fn] = f4_t{0.f, 0.f, 0.f, 0.f};
#pragma unroll
    for (int ks = 0; ks < 2; ++ks) {
      bf8_t b[4];
#pragma unroll
      for (int fn = 0; fn < 4; ++fn)
        b[fn] = *chunk(Kt[cur], fn * 16 + li, ks * 4 + g);
#pragma unroll
      for (int fn = 0; fn < 4; ++fn)
        s4[fn] = __builtin_amdgcn_mfma_f32_16x16x32_bf16(q3[ks], b[fn], s4[fn], 0, 0, 0);
    }

    // gather cp/pc from LDS; scale
    float sc[4][4];
#pragma unroll
    for (int fn = 0; fn < 4; ++fn)
#pragma unroll
      for (int r = 0; r < 4; ++r) {
        const int i_loc = w * 16 + g * 4 + r;
        const int j_loc = fn * 16 + li;
        const int d = (j0 + j_loc) - (i0 + i_loc);
        int rc = d;   if (rc > 512) rc = 512;   if (rc < -512) rc = -512;   rc += 512;
        int rc2 = -d; if (rc2 > 512) rc2 = 512; if (rc2 < -512) rc2 = -512; rc2 += 512;
        float v = s4[fn][r] + bf2f(TcpL[i_loc][rc - rbase])
                            + bf2f(Tpc[j_loc][rc2 - rbase2]);
        sc[fn][r] = v * SCALE_;
      }

    // online softmax (rows replicated over 16 lanes li)
    float fac[4];
#pragma unroll
    for (int r = 0; r < 4; ++r) {
      float mx = fmaxf(fmaxf(sc[0][r], sc[1][r]), fmaxf(sc[2][r], sc[3][r]));
#pragma unroll
      for (int off = 1; off < 16; off <<= 1) mx = fmaxf(mx, __shfl_xor(mx, off));
      float mnew = fmaxf(m_r[r], mx);
      fac[r] = __expf(m_r[r] - mnew);
      float rs = 0.f;
#pragma unroll
      for (int fn = 0; fn < 4; ++fn) { sc[fn][r] = __expf(sc[fn][r] - mnew); rs += sc[fn][r]; }
#pragma unroll
      for (int off = 1; off < 16; off <<= 1) rs += __shfl_xor(rs, off);
      l_r[r] = l_r[r] * fac[r] + rs;
      m_r[r] = mnew;
    }
#pragma unroll
    for (int fn = 0; fn < 4; ++fn)
#pragma unroll
      for (int r = 0; r < 4; ++r) acc_o[fn][r] *= fac[r];

    // write P (bf16) to swizzled per-wave LDS
#pragma unroll
    for (int fn = 0; fn < 4; ++fn)
#pragma unroll
      for (int r = 0; r < 4; ++r) {
        const int row = w * 16 + g * 4 + r;
        int byte = row * 128 + (fn * 16 + li) * 2;
        byte ^= (row & 7) << 4;
        *(unsigned short*)((char*)Pl + byte) = f2bf(sc[fn][r]);
      }

    // PV: acc_o += P(16x64) @ V^T  (A from Pl, B from swizzled V_lds)
#pragma unroll
    for (int ks = 0; ks < 2; ++ks) {
      const int arow = w * 16 + li;
      int abyte = arow * 128 + ks * 64 + g * 16;
      abyte ^= (arow & 7) << 4;
      bf8_t a = *(const bf8_t*)((const char*)Pl + abyte);
      bf8_t b[4];
#pragma unroll
      for (int fn2 = 0; fn2 < 4; ++fn2)
        b[fn2] = *chunk(Vl[cur], fn2 * 16 + li, ks * 4 + g);
#pragma unroll
      for (int fn2 = 0; fn2 < 4; ++fn2)
        acc_o[fn2] = __builtin_amdgcn_mfma_f32_16x16x32_bf16(a, b[fn2], acc_o[fn2], 0, 0, 0);
    }
  }

  // epilogue: normalize, write ctx [B*S, E] bf16
#pragma unroll
  for (int fn2 = 0; fn2 < 4; ++fn2)
#pragma unroll
    for (int r = 0; r < 4; ++r) {
      const int row = i0 + w * 16 + g * 4 + r;
      const int d = fn2 * 16 + li;
      float v = acc_o[fn2][r] / l_r[r];
      ctx[((long)bb * 1024 + row) * 768 + h * 64 + d] = f2bf(v);
    }
}

// ---------------- host launch ---------------------------------------------
extern "C" void kernel_launch(void* const* d_in, const int* in_sizes, int n_in,
                              void* d_out, int out_size, void* d_ws, size_t ws_size,
                              hipStream_t stream)
{
  const float* x   = (const float*)d_in[0];
  const float* Wq  = (const float*)d_in[1];
  const float* bq  = (const float*)d_in[2];
  const float* Wk  = (const float*)d_in[3];
  const float* bk  = (const float*)d_in[4];
  const float* Wv  = (const float*)d_in[5];
  const float* bv  = (const float*)d_in[6];
  const float* Wpq = (const float*)d_in[7];
  const float* bpq = (const float*)d_in[8];
  const float* Wpk = (const float*)d_in[9];
  const float* bpk = (const float*)d_in[10];
  const float* rel = (const float*)d_in[11];
  const float* Wo  = (const float*)d_in[12];
  const float* bo  = (const float*)d_in[13];

  char* ws = (char*)d_ws;
  auto alloc = [&](size_t bytes) { char* p = ws; ws += (bytes + 255) & ~(size_t)255; return p; };
  unsigned short* xb   = (unsigned short*)alloc((size_t)4096 * 768 * 2);
  unsigned short* Wqb  = (unsigned short*)alloc((size_t)768 * 768 * 2);
  unsigned short* Wkb  = (unsigned short*)alloc((size_t)768 * 768 * 2);
  unsigned short* Wvb  = (unsigned short*)alloc((size_t)768 * 768 * 2);
  unsigned short* Wpqb = (unsigned short*)alloc((size_t)768 * 768 * 2);
  unsigned short* Wpkb = (unsigned short*)alloc((size_t)768 * 768 * 2);
  unsigned short* Wob  = (unsigned short*)alloc((size_t)768 * 768 * 2);
  unsigned short* relb = (unsigned short*)alloc((size_t)1025 * 768 * 2);
  unsigned short* Qb   = (unsigned short*)alloc((size_t)48 * 1024 * 64 * 2);  // [B,H,S,D]
  unsigned short* Kb   = (unsigned short*)alloc((size_t)48 * 1024 * 64 * 2);  // [B,H,S,D]
  unsigned short* Vt   = (unsigned short*)alloc((size_t)48 * 64 * 1024 * 2);  // [B,H,D,S]
  unsigned short* qrb  = (unsigned short*)alloc((size_t)12 * 1025 * 64 * 2);  // [H,R,D]
  unsigned short* krb  = (unsigned short*)alloc((size_t)12 * 1025 * 64 * 2);
  unsigned short* ctx  = (unsigned short*)alloc((size_t)4096 * 768 * 2);      // [B*S, E]

  CvtArgs ca;
  const float* srcs[8] = {x, Wq, Wk, Wv, Wpq, Wpk, Wo, rel};
  unsigned short* dsts[8] = {xb, Wqb, Wkb, Wvb, Wpqb, Wpkb, Wob, relb};
  const int nch[8] = {786432, 147456, 147456, 147456, 147456, 147456, 147456, 196800};
  int total = 0;
  for (int i = 0; i < 8; ++i) { ca.src[i] = srcs[i]; ca.dst[i] = dsts[i]; ca.nchunks[i] = nch[i]; total += nch[i]; }
  cvt_kernel<<<dim3(2048), dim3(256), 0, stream>>>(ca, total);

  dim3 blk(256);
  // content projections: [4096,768] x [768,768]^T
  gemm_bt<MQKV><<<dim3(6, 64, 1), blk, 0, stream>>>(xb, 768, 0, Wqb, 768, 0, Qb, bq, 4096, 768, 768);
  gemm_bt<MQKV><<<dim3(6, 64, 1), blk, 0, stream>>>(xb, 768, 0, Wkb, 768, 0, Kb, bk, 4096, 768, 768);
  gemm_bt<MVT ><<<dim3(6, 64, 1), blk, 0, stream>>>(xb, 768, 0, Wvb, 768, 0, Vt, bv, 4096, 768, 768);
  // positional projections: [1025,768] x [768,768]^T
  gemm_bt<MREL><<<dim3(6, 17, 1), blk, 0, stream>>>(relb, 768, 0, Wpqb, 768, 0, qrb, bpq, 1025, 768, 768);
  gemm_bt<MREL><<<dim3(6, 17, 1), blk, 0, stream>>>(relb, 768, 0, Wpkb, 768, 0, krb, bpk, 1025, 768, 768);
  // fused scores(cc+cp+pc) + softmax + PV  (768 blocks, XCD-swizzled)
  flash_kernel<<<dim3(768), blk, 0, stream>>>(Qb, Kb, krb, qrb, Vt, ctx);
  // output projection: [4096,768] x [768,768]^T -> fp32 d_out
  gemm_bt<MOUT><<<dim3(6, 64, 1), blk, 0, stream>>>(ctx, 768, 0, Wob, 768, 0, d_out, bo, 4096, 768, 768);

  (void)in_sizes; (void)n_in; (void)out_size; (void)ws_size;
}

// Round 7
// 272.777 us; speedup vs baseline: 1.4390x; 1.1377x over previous
//
#include <hip/hip_runtime.h>
#include <stdint.h>

typedef __attribute__((ext_vector_type(8))) short bf8_t;   // 8 x bf16 (raw bits)
typedef __attribute__((ext_vector_type(4))) float f4_t;

#define DEV __device__ __forceinline__

constexpr int S_ = 1024;
constexpr int R_ = 1025;          // 2K+1
constexpr float SCALE_ = 0.07216878364870322f;  // 1/sqrt(3*64)

DEV float bf2f(unsigned short u) { union { unsigned int i; float f; } v; v.i = ((unsigned int)u) << 16; return v.f; }
DEV unsigned short f2bf(float f) {
  union { float fv; unsigned int i; } v; v.fv = f;
  unsigned int r = v.i + 0x7FFFu + ((v.i >> 16) & 1u);
  return (unsigned short)(r >> 16);
}

DEV void gll16(const unsigned short* g, unsigned short* l) {
  __builtin_amdgcn_global_load_lds(
      (const __attribute__((address_space(1))) unsigned int*)g,
      (__attribute__((address_space(3))) unsigned int*)l, 16, 0, 0);
}

// ---------------- fp32 -> bf16 bulk conversion (8 tensors, one launch) ----
struct CvtArgs { const float* src[8]; unsigned short* dst[8]; int nchunks[8]; };

__global__ __launch_bounds__(256) void cvt_kernel(CvtArgs a, int total) {
  int idx = blockIdx.x * 256 + threadIdx.x;
  int step = gridDim.x * 256;
  for (; idx < total; idx += step) {
    int c = idx, s = 0;
    while (c >= a.nchunks[s]) { c -= a.nchunks[s]; ++s; }
    float4 v = ((const float4*)a.src[s])[c];
    ushort4 o;
    o.x = f2bf(v.x); o.y = f2bf(v.y); o.z = f2bf(v.z); o.w = f2bf(v.w);
    ((ushort4*)a.dst[s])[c] = o;
  }
}

// ---- generic bf16 GEMM: C = A * B^T (+bias), gll16 staging, 64x128 tile --
enum { MQKV = 0, MVT = 1, MREL = 2, MCTX = 3, MOUT = 4 };

template <int MODE>
__global__ __launch_bounds__(256) void gemm_bt(
    const unsigned short* __restrict__ A, int lda, long abst,
    const unsigned short* __restrict__ B, int ldb, long bbst,
    void* __restrict__ C, const float* __restrict__ bias,
    int M, int N, int Kd)
{
  // BM=64, BN=128, BK=32 shorts (64B rows = 4 chunks of 16B)
  __shared__ unsigned short At[64 * 32];    // 4KB, chunk-swizzled: chunk ^= (row>>1)&3
  __shared__ unsigned short Bt[128 * 32];   // 8KB
  const int tid = threadIdx.x, lane = tid & 63, w = tid >> 6;
  const int li = lane & 15, g = lane >> 4;
  const int wr = w >> 1, wc = w & 1;
  const int sk = (li >> 1) & 3;             // read-side swizzle key
  const int m0 = blockIdx.y * 64, n0 = blockIdx.x * 128;
  const int z = blockIdx.z;
  const unsigned short* Ab = A + (long)z * abst;
  const unsigned short* Bb = B + (long)z * bbst;

  // staging: chunk index c -> row=c>>2, phys chunk p=c&3, logical l = p ^ ((row>>1)&3)
  const int arow = tid >> 2, ap = tid & 3;
  const int al = ap ^ ((arow >> 1) & 3);
  const long asrc = (long)min(m0 + arow, M - 1) * lda + al * 8;
  const int brow0 = tid >> 2, bl0 = (tid & 3) ^ ((brow0 >> 1) & 3);
  const int brow1 = (tid + 256) >> 2, bl1 = (tid & 3) ^ ((brow1 >> 1) & 3);
  const long bsrc0 = (long)min(n0 + brow0, N - 1) * ldb + bl0 * 8;
  const long bsrc1 = (long)min(n0 + brow1, N - 1) * ldb + bl1 * 8;

  f4_t acc[2][4];
#pragma unroll
  for (int i = 0; i < 2; ++i)
#pragma unroll
    for (int j = 0; j < 4; ++j) acc[i][j] = f4_t{0.f, 0.f, 0.f, 0.f};

  for (int k0 = 0; k0 < Kd; k0 += 32) {
    gll16(Ab + asrc + k0,  At + w * 512 + lane * 8);
    gll16(Bb + bsrc0 + k0, Bt + w * 512 + lane * 8);
    gll16(Bb + bsrc1 + k0, Bt + 2048 + w * 512 + lane * 8);
    asm volatile("s_waitcnt vmcnt(0)" ::: "memory");
    __syncthreads();

    bf8_t a[2], b[4];
#pragma unroll
    for (int fm = 0; fm < 2; ++fm) {
      int row = wr * 32 + fm * 16 + li;
      a[fm] = *(const bf8_t*)(At + row * 32 + (g ^ sk) * 8);
    }
#pragma unroll
    for (int fn = 0; fn < 4; ++fn) {
      int row = wc * 64 + fn * 16 + li;
      b[fn] = *(const bf8_t*)(Bt + row * 32 + (g ^ sk) * 8);
    }
#pragma unroll
    for (int fm = 0; fm < 2; ++fm)
#pragma unroll
      for (int fn = 0; fn < 4; ++fn)
        acc[fm][fn] = __builtin_amdgcn_mfma_f32_16x16x32_bf16(a[fm], b[fn], acc[fm][fn], 0, 0, 0);
    __syncthreads();
  }

#pragma unroll
  for (int fm = 0; fm < 2; ++fm)
#pragma unroll
    for (int fn = 0; fn < 4; ++fn)
#pragma unroll
      for (int r = 0; r < 4; ++r) {
        int row = wr * 32 + fm * 16 + (lane >> 4) * 4 + r;
        int col = wc * 64 + fn * 16 + li;
        int m = m0 + row, n = n0 + col;
        if (m >= M || n >= N) continue;
        float v = acc[fm][fn][r];
        if (bias) v += bias[n];
        long off;
        if constexpr (MODE == MQKV)      off = (long)((m >> 10) * 12 + (n >> 6)) * 65536 + (m & 1023) * 64 + (n & 63);
        else if constexpr (MODE == MVT)  off = (long)((m >> 10) * 12 + (n >> 6)) * 65536 + (n & 63) * 1024 + (m & 1023);
        else if constexpr (MODE == MREL) off = (long)(n >> 6) * (R_ * 64) + (long)m * 64 + (n & 63);
        else if constexpr (MODE == MCTX) { int bb = z / 12, hh = z - bb * 12; off = (long)bb * 786432 + (long)m * 768 + hh * 64 + n; }
        else                             off = (long)m * 768 + n;
        if constexpr (MODE == MOUT) ((float*)C)[off] = v;
        else                        ((unsigned short*)C)[off] = f2bf(v);
      }
}

// ------- fused flash: cc + cp(per-wave regs) + pc(on-chip) + softmax + PV --
__global__ __launch_bounds__(256) void flash_kernel(
    const unsigned short* __restrict__ Q, const unsigned short* __restrict__ Kc,
    const unsigned short* __restrict__ kr, const unsigned short* __restrict__ qr,
    const unsigned short* __restrict__ Vt, unsigned short* __restrict__ ctx)
{
  // bijective XCD swizzle: each XCD owns 6 whole bh (all 16 i-tiles together)
  const int flat = blockIdx.x;
  const int logical = (flat & 7) * 96 + (flat >> 3);
  const int bh = logical >> 4, h = bh % 12, bb = bh / 12;
  const int i0 = (logical & 15) * 64;
  const int tid = threadIdx.x, lane = tid & 63, w = tid >> 6;
  const int g = lane >> 4, li = lane & 15;
  const unsigned short* Qb  = Q  + (long)bh * (S_ * 64);
  const unsigned short* Kb  = Kc + (long)bh * (S_ * 64);
  const unsigned short* Vb  = Vt + (long)bh * (S_ * 64);   // [64 d][1024 s]
  const unsigned short* krh = kr + (long)h * (R_ * 64);
  const unsigned short* qrh = qr + (long)h * (R_ * 64);

  __shared__ unsigned short Kt[4096];        // single buf, 64x64, XOR-swizzled chunks
  __shared__ unsigned short Vl[4096];        // single buf
  __shared__ unsigned short Tpc[64][132];    // pad-4: conflict-free writes & diag reads
  __shared__ unsigned short TcpW[4][16][80]; // per-wave cp window strips
  __shared__ unsigned short Pl[4096];        // per-wave P rows, XOR-swizzled

  const int mh = w & 1, nq = w >> 1;

  // stage K-tile + V-tile for tile jt (source-preswizzled, linear LDS dest)
  const int sr0 = w * 8 + (lane >> 3);
  const int scc = (lane & 7) ^ (sr0 & 7);      // same for sr0 and sr0+32
  auto stage = [&](int jt) {
    const int j0n = jt * 64;
    gll16(Kb + (long)(j0n + sr0) * 64 + scc * 8,        &Kt[w * 512 + lane * 8]);
    gll16(Kb + (long)(j0n + sr0 + 32) * 64 + scc * 8,   &Kt[w * 512 + 2048 + lane * 8]);
    gll16(Vb + (long)sr0 * 1024 + j0n + scc * 8,        &Vl[w * 512 + lane * 8]);
    gll16(Vb + (long)(sr0 + 32) * 1024 + j0n + scc * 8, &Vl[w * 512 + 2048 + lane * 8]);
  };
  auto chunk = [&](const unsigned short* base, int row, int ck) -> const bf8_t* {
    return (const bf8_t*)((const char*)base + row * 128 + ((ck ^ (row & 7)) << 4));
  };

  // hoisted Q fragments: wave w owns rows i0 + w*16 .. +16 (A for Tcp AND cc)
  bf8_t q3[2];
#pragma unroll
  for (int ks = 0; ks < 2; ++ks)
    q3[ks] = *(const bf8_t*)(Qb + (long)(i0 + w * 16 + li) * 64 + ks * 32 + g * 8);

  float m_r[4], l_r[4];
  f4_t acc_o[4];
#pragma unroll
  for (int r = 0; r < 4; ++r) { m_r[r] = -1e30f; l_r[r] = 0.f; }
#pragma unroll
  for (int fn = 0; fn < 4; ++fn) acc_o[fn] = f4_t{0.f, 0.f, 0.f, 0.f};

  stage(0);

  for (int jt = 0; jt < 16; ++jt) {
    const int j0 = jt * 64;
    const int Dl = j0 - i0;
    const int rbase2 = min(max(-Dl - 63, -512), 512) + 512;
    // per-wave cp window base: d spans [Dl - w*16 - 15, Dl - w*16 + 63] (79 wide)
    const int wb = min(max(Dl - w * 16 - 15, -512), 512) + 512;

    { // Tcp phase (registers + own strip; no K/V dependency — covers stage latency)
      f4_t at[5];
#pragma unroll
      for (int f5 = 0; f5 < 5; ++f5) at[f5] = f4_t{0.f, 0.f, 0.f, 0.f};
#pragma unroll
      for (int ks = 0; ks < 2; ++ks) {
        bf8_t b[5];
#pragma unroll
        for (int f5 = 0; f5 < 5; ++f5) {
          int krow = wb + f5 * 16 + li;
          if (krow > 1024) krow = 1024;
          b[f5] = *(const bf8_t*)(krh + (long)krow * 64 + ks * 32 + g * 8);
        }
#pragma unroll
        for (int f5 = 0; f5 < 5; ++f5)
          at[f5] = __builtin_amdgcn_mfma_f32_16x16x32_bf16(q3[ks], b[f5], at[f5], 0, 0, 0);
      }
#pragma unroll
      for (int f5 = 0; f5 < 5; ++f5)
#pragma unroll
        for (int r = 0; r < 4; ++r)
          TcpW[w][g * 4 + r][f5 * 16 + li] = f2bf(at[f5][r]);
    }

    asm volatile("s_waitcnt vmcnt(0)" ::: "memory");
    __builtin_amdgcn_s_barrier();              // A: K,V staged & visible

    { // Tpc = Ktile(64x64) @ qrWin(128x64)^T  (A from swizzled LDS, B global/L2)
      f4_t acc[2][4];
#pragma unroll
      for (int i = 0; i < 2; ++i)
#pragma unroll
        for (int j = 0; j < 4; ++j) acc[i][j] = f4_t{0.f, 0.f, 0.f, 0.f};
#pragma unroll
      for (int ks = 0; ks < 2; ++ks) {
        bf8_t a[2], b[4];
#pragma unroll
        for (int fm = 0; fm < 2; ++fm)
          a[fm] = *chunk(Kt, mh * 32 + fm * 16 + li, ks * 4 + g);
#pragma unroll
        for (int fn = 0; fn < 4; ++fn) {
          int krow = rbase2 + nq * 64 + fn * 16 + li;
          if (krow > 1024) krow = 1024;
          b[fn] = *(const bf8_t*)(qrh + (long)krow * 64 + ks * 32 + g * 8);
        }
#pragma unroll
        for (int fm = 0; fm < 2; ++fm)
#pragma unroll
          for (int fn = 0; fn < 4; ++fn)
            acc[fm][fn] = __builtin_amdgcn_mfma_f32_16x16x32_bf16(a[fm], b[fn], acc[fm][fn], 0, 0, 0);
      }
#pragma unroll
      for (int fm = 0; fm < 2; ++fm)
#pragma unroll
        for (int fn = 0; fn < 4; ++fn)
#pragma unroll
          for (int r = 0; r < 4; ++r)
            Tpc[mh * 32 + fm * 16 + g * 4 + r][nq * 64 + fn * 16 + li] = f2bf(acc[fm][fn][r]);
    }

    asm volatile("s_waitcnt lgkmcnt(0)" ::: "memory");
    __builtin_amdgcn_s_barrier();              // B: Tpc (and own strip) visible

    // cc MFMA — wave w: rows [w*16, w*16+16), all 64 cols, K from swizzled LDS
    f4_t s4[4];
#pragma unroll
    for (int fn = 0; fn < 4; ++fn) s4[fn] = f4_t{0.f, 0.f, 0.f, 0.f};
#pragma unroll
    for (int ks = 0; ks < 2; ++ks) {
      bf8_t b[4];
#pragma unroll
      for (int fn = 0; fn < 4; ++fn)
        b[fn] = *chunk(Kt, fn * 16 + li, ks * 4 + g);
#pragma unroll
      for (int fn = 0; fn < 4; ++fn)
        s4[fn] = __builtin_amdgcn_mfma_f32_16x16x32_bf16(q3[ks], b[fn], s4[fn], 0, 0, 0);
    }

    // gather cp (own strip) + pc (Tpc); scale
    float sc[4][4];
#pragma unroll
    for (int fn = 0; fn < 4; ++fn)
#pragma unroll
      for (int r = 0; r < 4; ++r) {
        const int iL = g * 4 + r;
        const int j_loc = fn * 16 + li;
        const int d = (j0 + j_loc) - (i0 + w * 16 + iL);
        int rc = d;   if (rc > 512) rc = 512;   if (rc < -512) rc = -512;   rc += 512;
        int rc2 = -d; if (rc2 > 512) rc2 = 512; if (rc2 < -512) rc2 = -512; rc2 += 512;
        float v = s4[fn][r] + bf2f(TcpW[w][iL][rc - wb])
                            + bf2f(Tpc[j_loc][rc2 - rbase2]);
        sc[fn][r] = v * SCALE_;
      }

    // online softmax (rows replicated over 16 lanes li)
    float fac[4];
#pragma unroll
    for (int r = 0; r < 4; ++r) {
      float mx = fmaxf(fmaxf(sc[0][r], sc[1][r]), fmaxf(sc[2][r], sc[3][r]));
#pragma unroll
      for (int off = 1; off < 16; off <<= 1) mx = fmaxf(mx, __shfl_xor(mx, off));
      float mnew = fmaxf(m_r[r], mx);
      fac[r] = __expf(m_r[r] - mnew);
      float rs = 0.f;
#pragma unroll
      for (int fn = 0; fn < 4; ++fn) { sc[fn][r] = __expf(sc[fn][r] - mnew); rs += sc[fn][r]; }
#pragma unroll
      for (int off = 1; off < 16; off <<= 1) rs += __shfl_xor(rs, off);
      l_r[r] = l_r[r] * fac[r] + rs;
      m_r[r] = mnew;
    }
#pragma unroll
    for (int fn = 0; fn < 4; ++fn)
#pragma unroll
      for (int r = 0; r < 4; ++r) acc_o[fn][r] *= fac[r];

    // write P (bf16) to swizzled per-wave LDS
#pragma unroll
    for (int fn = 0; fn < 4; ++fn)
#pragma unroll
      for (int r = 0; r < 4; ++r) {
        const int row = w * 16 + g * 4 + r;
        int byte = row * 128 + (fn * 16 + li) * 2;
        byte ^= (row & 7) << 4;
        *(unsigned short*)((char*)Pl + byte) = f2bf(sc[fn][r]);
      }

    // PV: acc_o += P(16x64) @ V^T  (A from Pl own rows, B from swizzled V_lds)
#pragma unroll
    for (int ks = 0; ks < 2; ++ks) {
      const int arow = w * 16 + li;
      int abyte = arow * 128 + ks * 64 + g * 16;
      abyte ^= (arow & 7) << 4;
      bf8_t a = *(const bf8_t*)((const char*)Pl + abyte);
      bf8_t b[4];
#pragma unroll
      for (int fn2 = 0; fn2 < 4; ++fn2)
        b[fn2] = *chunk(Vl, fn2 * 16 + li, ks * 4 + g);
#pragma unroll
      for (int fn2 = 0; fn2 < 4; ++fn2)
        acc_o[fn2] = __builtin_amdgcn_mfma_f32_16x16x32_bf16(a, b[fn2], acc_o[fn2], 0, 0, 0);
    }

    if (jt + 1 < 16) {
      __builtin_amdgcn_s_barrier();            // C: all waves done reading K/V
      stage(jt + 1);                            // latency covered by next Tcp phase
    }
  }

  // epilogue: normalize, write ctx [B*S, E] bf16
#pragma unroll
  for (int fn2 = 0; fn2 < 4; ++fn2)
#pragma unroll
    for (int r = 0; r < 4; ++r) {
      const int row = i0 + w * 16 + g * 4 + r;
      const int d = fn2 * 16 + li;
      float v = acc_o[fn2][r] / l_r[r];
      ctx[((long)bb * 1024 + row) * 768 + h * 64 + d] = f2bf(v);
    }
}

// ---------------- host launch ---------------------------------------------
extern "C" void kernel_launch(void* const* d_in, const int* in_sizes, int n_in,
                              void* d_out, int out_size, void* d_ws, size_t ws_size,
                              hipStream_t stream)
{
  const float* x   = (const float*)d_in[0];
  const float* Wq  = (const float*)d_in[1];
  const float* bq  = (const float*)d_in[2];
  const float* Wk  = (const float*)d_in[3];
  const float* bk  = (const float*)d_in[4];
  const float* Wv  = (const float*)d_in[5];
  const float* bv  = (const float*)d_in[6];
  const float* Wpq = (const float*)d_in[7];
  const float* bpq = (const float*)d_in[8];
  const float* Wpk = (const float*)d_in[9];
  const float* bpk = (const float*)d_in[10];
  const float* rel = (const float*)d_in[11];
  const float* Wo  = (const float*)d_in[12];
  const float* bo  = (const float*)d_in[13];

  char* ws = (char*)d_ws;
  auto alloc = [&](size_t bytes) { char* p = ws; ws += (bytes + 255) & ~(size_t)255; return p; };
  unsigned short* xb   = (unsigned short*)alloc((size_t)4096 * 768 * 2);
  unsigned short* Wqb  = (unsigned short*)alloc((size_t)768 * 768 * 2);
  unsigned short* Wkb  = (unsigned short*)alloc((size_t)768 * 768 * 2);
  unsigned short* Wvb  = (unsigned short*)alloc((size_t)768 * 768 * 2);
  unsigned short* Wpqb = (unsigned short*)alloc((size_t)768 * 768 * 2);
  unsigned short* Wpkb = (unsigned short*)alloc((size_t)768 * 768 * 2);
  unsigned short* Wob  = (unsigned short*)alloc((size_t)768 * 768 * 2);
  unsigned short* relb = (unsigned short*)alloc((size_t)1025 * 768 * 2);
  unsigned short* Qb   = (unsigned short*)alloc((size_t)48 * 1024 * 64 * 2);  // [B,H,S,D]
  unsigned short* Kb   = (unsigned short*)alloc((size_t)48 * 1024 * 64 * 2);  // [B,H,S,D]
  unsigned short* Vt   = (unsigned short*)alloc((size_t)48 * 64 * 1024 * 2);  // [B,H,D,S]
  unsigned short* qrb  = (unsigned short*)alloc((size_t)12 * 1025 * 64 * 2);  // [H,R,D]
  unsigned short* krb  = (unsigned short*)alloc((size_t)12 * 1025 * 64 * 2);
  unsigned short* ctx  = (unsigned short*)alloc((size_t)4096 * 768 * 2);      // [B*S, E]

  CvtArgs ca;
  const float* srcs[8] = {x, Wq, Wk, Wv, Wpq, Wpk, Wo, rel};
  unsigned short* dsts[8] = {xb, Wqb, Wkb, Wvb, Wpqb, Wpkb, Wob, relb};
  const int nch[8] = {786432, 147456, 147456, 147456, 147456, 147456, 147456, 196800};
  int total = 0;
  for (int i = 0; i < 8; ++i) { ca.src[i] = srcs[i]; ca.dst[i] = dsts[i]; ca.nchunks[i] = nch[i]; total += nch[i]; }
  cvt_kernel<<<dim3(2048), dim3(256), 0, stream>>>(ca, total);

  dim3 blk(256);
  // content projections: [4096,768] x [768,768]^T
  gemm_bt<MQKV><<<dim3(6, 64, 1), blk, 0, stream>>>(xb, 768, 0, Wqb, 768, 0, Qb, bq, 4096, 768, 768);
  gemm_bt<MQKV><<<dim3(6, 64, 1), blk, 0, stream>>>(xb, 768, 0, Wkb, 768, 0, Kb, bk, 4096, 768, 768);
  gemm_bt<MVT ><<<dim3(6, 64, 1), blk, 0, stream>>>(xb, 768, 0, Wvb, 768, 0, Vt, bv, 4096, 768, 768);
  // positional projections: [1025,768] x [768,768]^T
  gemm_bt<MREL><<<dim3(6, 17, 1), blk, 0, stream>>>(relb, 768, 0, Wpqb, 768, 0, qrb, bpq, 1025, 768, 768);
  gemm_bt<MREL><<<dim3(6, 17, 1), blk, 0, stream>>>(relb, 768, 0, Wpkb, 768, 0, krb, bpk, 1025, 768, 768);
  // fused scores(cc+cp+pc) + softmax + PV  (768 blocks, XCD-swizzled, 3/CU)
  flash_kernel<<<dim3(768), blk, 0, stream>>>(Qb, Kb, krb, qrb, Vt, ctx);
  // output projection: [4096,768] x [768,768]^T -> fp32 d_out
  gemm_bt<MOUT><<<dim3(6, 64, 1), blk, 0, stream>>>(ctx, 768, 0, Wob, 768, 0, d_out, bo, 4096, 768, 768);

  (void)in_sizes; (void)n_in; (void)out_size; (void)ws_size;
}

// Round 8
// 254.202 us; speedup vs baseline: 1.5441x; 1.0731x over previous
//
#include <hip/hip_runtime.h>
#include <stdint.h>

typedef __attribute__((ext_vector_type(8))) short bf8_t;   // 8 x bf16 (raw bits)
typedef __attribute__((ext_vector_type(4))) float f4_t;

#define DEV __device__ __forceinline__

constexpr int S_ = 1024;
constexpr float SCALE2_ = 0.104117584f;   // 1/sqrt(192) * log2(e)

DEV float bf2f(unsigned short u) { union { unsigned int i; float f; } v; v.i = ((unsigned int)u) << 16; return v.f; }
DEV unsigned short f2bf(float f) {
  union { float fv; unsigned int i; } v; v.fv = f;
  unsigned int r = v.i + 0x7FFFu + ((v.i >> 16) & 1u);
  return (unsigned short)(r >> 16);
}

DEV void gll16(const unsigned short* g, unsigned short* l) {
  __builtin_amdgcn_global_load_lds(
      (const __attribute__((address_space(1))) unsigned int*)g,
      (__attribute__((address_space(3))) unsigned int*)l, 16, 0, 0);
}

// 128B-row LDS tile, chunk-XOR swizzled
DEV const bf8_t* chunk128(const unsigned short* base, int row, int ck) {
  return (const bf8_t*)((const char*)base + row * 128 + (((ck ^ row) & 7) << 4));
}

// ---------------- fp32 -> bf16 bulk conversion (8 tensors, one launch) ----
struct CvtArgs { const float* src[8]; unsigned short* dst[8]; int nchunks[8]; };

__global__ __launch_bounds__(256) void cvt_kernel(CvtArgs a, int total) {
  int idx = blockIdx.x * 256 + threadIdx.x;
  int step = gridDim.x * 256;
  for (; idx < total; idx += step) {
    int c = idx, s = 0;
    while (c >= a.nchunks[s]) { c -= a.nchunks[s]; ++s; }
    float4 v = ((const float4*)a.src[s])[c];
    ushort4 o;
    o.x = f2bf(v.x); o.y = f2bf(v.y); o.z = f2bf(v.z); o.w = f2bf(v.w);
    ((ushort4*)a.dst[s])[c] = o;
  }
}

// ---- bf16 GEMM: C = A * B^T (+bias), BK=64 gll16 staging, 64x128 tile ----
enum { MQKVF = 0, MRELF = 1, MOUT = 2 };

template <int MODE>
__global__ __launch_bounds__(256) void gemm_bt(
    const unsigned short* __restrict__ A, int lda,
    const unsigned short* __restrict__ B, int ldb,
    void* __restrict__ C,
    const float* __restrict__ b0, const float* __restrict__ b1, const float* __restrict__ b2,
    int M, int N, int Kd)
{
  __shared__ unsigned short At[64 * 64];    // 8KB, 128B rows, chunk-swizzled
  __shared__ unsigned short Bt[128 * 64];   // 16KB
  const int tid = threadIdx.x, lane = tid & 63, w = tid >> 6;
  const int li = lane & 15, g = lane >> 4;
  const int wr = w >> 1, wc = w & 1;
  const int m0 = blockIdx.y * 64, n0 = blockIdx.x * 128;

  // staging: chunk c -> row=c>>3, phys p=c&7, logical l = p ^ (row&7)
  const int srow = tid >> 3;
  const int sl = (tid & 7) ^ (srow & 7);
  const long aoff0 = (long)min(m0 + srow,      M - 1) * lda + sl * 8;
  const long aoff1 = (long)min(m0 + srow + 32, M - 1) * lda + sl * 8;
  const long boff0 = (long)min(n0 + srow,      N - 1) * ldb + sl * 8;
  const long boff1 = (long)min(n0 + srow + 32, N - 1) * ldb + sl * 8;
  const long boff2 = (long)min(n0 + srow + 64, N - 1) * ldb + sl * 8;
  const long boff3 = (long)min(n0 + srow + 96, N - 1) * ldb + sl * 8;

  f4_t acc[2][4];
#pragma unroll
  for (int i = 0; i < 2; ++i)
#pragma unroll
    for (int j = 0; j < 4; ++j) acc[i][j] = f4_t{0.f, 0.f, 0.f, 0.f};

  for (int k0 = 0; k0 < Kd; k0 += 64) {
    gll16(A + aoff0 + k0, At + tid * 8);
    gll16(A + aoff1 + k0, At + tid * 8 + 2048);
    gll16(B + boff0 + k0, Bt + tid * 8);
    gll16(B + boff1 + k0, Bt + tid * 8 + 2048);
    gll16(B + boff2 + k0, Bt + tid * 8 + 4096);
    gll16(B + boff3 + k0, Bt + tid * 8 + 6144);
    asm volatile("s_waitcnt vmcnt(0)" ::: "memory");
    __syncthreads();

#pragma unroll
    for (int ks = 0; ks < 2; ++ks) {
      bf8_t a[2], b[4];
#pragma unroll
      for (int fm = 0; fm < 2; ++fm)
        a[fm] = *chunk128(At, wr * 32 + fm * 16 + li, ks * 4 + g);
#pragma unroll
      for (int fn = 0; fn < 4; ++fn)
        b[fn] = *chunk128(Bt, wc * 64 + fn * 16 + li, ks * 4 + g);
#pragma unroll
      for (int fm = 0; fm < 2; ++fm)
#pragma unroll
        for (int fn = 0; fn < 4; ++fn)
          acc[fm][fn] = __builtin_amdgcn_mfma_f32_16x16x32_bf16(a[fm], b[fn], acc[fm][fn], 0, 0, 0);
    }
    __syncthreads();
  }

#pragma unroll
  for (int fm = 0; fm < 2; ++fm)
#pragma unroll
    for (int fn = 0; fn < 4; ++fn)
#pragma unroll
      for (int r = 0; r < 4; ++r) {
        int row = wr * 32 + fm * 16 + g * 4 + r;
        int col = wc * 64 + fn * 16 + li;
        int m = m0 + row, n = n0 + col;
        if (m >= M || n >= N) continue;
        float v = acc[fm][fn][r];
        if constexpr (MODE == MQKVF) {
          int sel = (n >= 1536) ? 2 : (n >= 768 ? 1 : 0);
          int nn = n - sel * 768;
          v += (sel == 0 ? b0 : sel == 1 ? b1 : b2)[nn];
          long off = (long)sel * 3145728 + (long)((m >> 10) * 12 + (nn >> 6)) * 65536;
          if (sel == 2) off += (nn & 63) * 1024 + (m & 1023);   // V transposed
          else          off += (m & 1023) * 64 + (nn & 63);
          ((unsigned short*)C)[off] = f2bf(v);
        } else if constexpr (MODE == MRELF) {
          int sel = n >= 768 ? 1 : 0;
          int nn = n - sel * 768;
          v += (sel ? b1 : b0)[nn];
          long off = (long)sel * 1572864 + (long)(nn >> 6) * 131072 + (long)(m + 511) * 64 + (nn & 63);
          ((unsigned short*)C)[off] = f2bf(v);
        } else {
          v += b0[n];
          ((float*)C)[(long)m * 768 + n] = v;
        }
      }
}

// ---- expand: replicate saturation rows of ext rel tables -----------------
// tables qkx = [2 tbl][12 h][2048 t][64 d]; center t in [511,1535] pre-written
__global__ __launch_bounds__(256) void expand_kernel(unsigned short* __restrict__ qkx) {
  int id = blockIdx.x * 256 + threadIdx.x;     // 196608 total
  int chunk = id & 7;
  int rr = (id >> 3) & 511;
  int half = (id >> 12) & 1;
  int th = id >> 13;                            // 0..23 (tbl*12 + h)
  unsigned short* base = qkx + (long)th * 131072;
  int dst = half ? 1536 + rr : rr;
  int src = half ? 1535 : 511;
  *(int4*)(base + dst * 64 + chunk * 8) = *(const int4*)(base + src * 64 + chunk * 8);
}

// ------- fused flash: cc + cp(per-wave strip) + pc + softmax + PV ---------
__global__ __launch_bounds__(256) void flash_kernel(
    const unsigned short* __restrict__ Q, const unsigned short* __restrict__ Kc,
    const unsigned short* __restrict__ krx, const unsigned short* __restrict__ qrx,
    const unsigned short* __restrict__ Vt, unsigned short* __restrict__ ctx)
{
  // bijective XCD swizzle: each XCD owns 6 whole bh (all 16 i-tiles together)
  const int flat = blockIdx.x;
  const int logical = (flat & 7) * 96 + (flat >> 3);
  const int bh = logical >> 4, h = bh % 12, bb = bh / 12;
  const int i0 = (logical & 15) * 64;
  const int tid = threadIdx.x, lane = tid & 63, w = tid >> 6;
  const int g = lane >> 4, li = lane & 15;
  const unsigned short* Qb  = Q  + (long)bh * (S_ * 64);
  const unsigned short* Kb  = Kc + (long)bh * (S_ * 64);
  const unsigned short* Vb  = Vt + (long)bh * (S_ * 64);   // [64 d][1024 s]
  const unsigned short* krh = krx + (long)h * 131072;      // ext [2048][64]
  const unsigned short* qrh = qrx + (long)h * 131072;

  __shared__ unsigned short Kt[4096];        // single buf, 64x64, XOR-swizzled chunks
  __shared__ unsigned short Vl[4096];        // single buf
  __shared__ unsigned short Tpc[64][132];
  __shared__ unsigned short TcpW[4][16][84]; // per-wave cp strips (42 dw/row: no 4-way)
  __shared__ unsigned short Pl[4096];        // per-wave P rows, XOR-swizzled

  const int mh = w & 1, nq = w >> 1;

  // stage K-tile + V-tile for tile jt (source-preswizzled, linear LDS dest)
  const int sr0 = w * 8 + (lane >> 3);
  const int scc = (lane & 7) ^ (sr0 & 7);
  auto stage = [&](int jt) {
    const int j0n = jt * 64;
    gll16(Kb + (long)(j0n + sr0) * 64 + scc * 8,        &Kt[w * 512 + lane * 8]);
    gll16(Kb + (long)(j0n + sr0 + 32) * 64 + scc * 8,   &Kt[w * 512 + 2048 + lane * 8]);
    gll16(Vb + (long)sr0 * 1024 + j0n + scc * 8,        &Vl[w * 512 + lane * 8]);
    gll16(Vb + (long)(sr0 + 32) * 1024 + j0n + scc * 8, &Vl[w * 512 + 2048 + lane * 8]);
  };

  // hoisted Q fragments: wave w owns rows i0 + w*16 .. +16
  bf8_t q3[2];
#pragma unroll
  for (int ks = 0; ks < 2; ++ks)
    q3[ks] = *(const bf8_t*)(Qb + (long)(i0 + w * 16 + li) * 64 + ks * 32 + g * 8);

  float m_r[4], l_r[4];
  f4_t acc_o[4];
#pragma unroll
  for (int r = 0; r < 4; ++r) { m_r[r] = -1e30f; l_r[r] = 0.f; }
#pragma unroll
  for (int fn = 0; fn < 4; ++fn) acc_o[fn] = f4_t{0.f, 0.f, 0.f, 0.f};

  const int base_cp = li + 15 - g * 4;          // + fn*16 - r
  const int base_pc = 63 + w * 16 + g * 4 - li; // + r - fn*16

  stage(0);

  for (int jt = 0; jt < 16; ++jt) {
    const int j0 = jt * 64;
    const int Dl = j0 - i0;
    const int wbE = Dl - w * 16 - 15 + 1023;    // ext-table window base (no clamp)
    const int rbE = -Dl - 63 + 1023;

    { // Tcp phase (regs + own strip; no K/V dep — covers stage latency)
      f4_t at[5];
#pragma unroll
      for (int f5 = 0; f5 < 5; ++f5) at[f5] = f4_t{0.f, 0.f, 0.f, 0.f};
#pragma unroll
      for (int ks = 0; ks < 2; ++ks) {
        bf8_t b[5];
#pragma unroll
        for (int f5 = 0; f5 < 5; ++f5)
          b[f5] = *(const bf8_t*)(krh + (long)(wbE + f5 * 16 + li) * 64 + ks * 32 + g * 8);
#pragma unroll
        for (int f5 = 0; f5 < 5; ++f5)
          at[f5] = __builtin_amdgcn_mfma_f32_16x16x32_bf16(q3[ks], b[f5], at[f5], 0, 0, 0);
      }
#pragma unroll
      for (int f5 = 0; f5 < 5; ++f5)
#pragma unroll
        for (int r = 0; r < 4; ++r)
          TcpW[w][g * 4 + r][f5 * 16 + li] = f2bf(at[f5][r]);
    }

    asm volatile("s_waitcnt vmcnt(0)" ::: "memory");
    __builtin_amdgcn_s_barrier();              // A: K,V staged & visible

    { // Tpc = Ktile(64x64) @ qrWin(128x64)^T
      f4_t acc[2][4];
#pragma unroll
      for (int i = 0; i < 2; ++i)
#pragma unroll
        for (int j = 0; j < 4; ++j) acc[i][j] = f4_t{0.f, 0.f, 0.f, 0.f};
#pragma unroll
      for (int ks = 0; ks < 2; ++ks) {
        bf8_t a[2], b[4];
#pragma unroll
        for (int fm = 0; fm < 2; ++fm)
          a[fm] = *chunk128(Kt, mh * 32 + fm * 16 + li, ks * 4 + g);
#pragma unroll
        for (int fn = 0; fn < 4; ++fn)
          b[fn] = *(const bf8_t*)(qrh + (long)(rbE + nq * 64 + fn * 16 + li) * 64 + ks * 32 + g * 8);
#pragma unroll
        for (int fm = 0; fm < 2; ++fm)
#pragma unroll
          for (int fn = 0; fn < 4; ++fn)
            acc[fm][fn] = __builtin_amdgcn_mfma_f32_16x16x32_bf16(a[fm], b[fn], acc[fm][fn], 0, 0, 0);
      }
#pragma unroll
      for (int fm = 0; fm < 2; ++fm)
#pragma unroll
        for (int fn = 0; fn < 4; ++fn)
#pragma unroll
          for (int r = 0; r < 4; ++r)
            Tpc[mh * 32 + fm * 16 + g * 4 + r][nq * 64 + fn * 16 + li] = f2bf(acc[fm][fn][r]);
    }

    asm volatile("s_waitcnt lgkmcnt(0)" ::: "memory");
    __builtin_amdgcn_s_barrier();              // B: Tpc visible

    // cc MFMA — wave w: rows [w*16, w*16+16), all 64 cols
    f4_t s4[4];
#pragma unroll
    for (int fn = 0; fn < 4; ++fn) s4[fn] = f4_t{0.f, 0.f, 0.f, 0.f};
#pragma unroll
    for (int ks = 0; ks < 2; ++ks) {
      bf8_t b[4];
#pragma unroll
      for (int fn = 0; fn < 4; ++fn)
        b[fn] = *chunk128(Kt, fn * 16 + li, ks * 4 + g);
#pragma unroll
      for (int fn = 0; fn < 4; ++fn)
        s4[fn] = __builtin_amdgcn_mfma_f32_16x16x32_bf16(q3[ks], b[fn], s4[fn], 0, 0, 0);
    }

    // gather cp (own strip) + pc (Tpc); clamp-free affine cols; log2-domain
    float sc[4][4];
#pragma unroll
    for (int fn = 0; fn < 4; ++fn)
#pragma unroll
      for (int r = 0; r < 4; ++r) {
        float v = s4[fn][r] + bf2f(TcpW[w][g * 4 + r][base_cp + fn * 16 - r])
                            + bf2f(Tpc[fn * 16 + li][base_pc + r - fn * 16]);
        sc[fn][r] = v * SCALE2_;
      }

    // online softmax, exp2 domain (rows replicated over 16 lanes li)
    float fac[4];
#pragma unroll
    for (int r = 0; r < 4; ++r) {
      float mx = fmaxf(fmaxf(sc[0][r], sc[1][r]), fmaxf(sc[2][r], sc[3][r]));
#pragma unroll
      for (int off = 1; off < 16; off <<= 1) mx = fmaxf(mx, __shfl_xor(mx, off));
      float mnew = fmaxf(m_r[r], mx);
      fac[r] = exp2f(m_r[r] - mnew);
      float rs = 0.f;
#pragma unroll
      for (int fn = 0; fn < 4; ++fn) { sc[fn][r] = exp2f(sc[fn][r] - mnew); rs += sc[fn][r]; }
#pragma unroll
      for (int off = 1; off < 16; off <<= 1) rs += __shfl_xor(rs, off);
      l_r[r] = l_r[r] * fac[r] + rs;
      m_r[r] = mnew;
    }
#pragma unroll
    for (int fn = 0; fn < 4; ++fn)
#pragma unroll
      for (int r = 0; r < 4; ++r) acc_o[fn][r] *= fac[r];

    // write P (bf16) to swizzled per-wave LDS
#pragma unroll
    for (int fn = 0; fn < 4; ++fn)
#pragma unroll
      for (int r = 0; r < 4; ++r) {
        const int row = w * 16 + g * 4 + r;
        int byte = row * 128 + (fn * 16 + li) * 2;
        byte ^= (row & 7) << 4;
        *(unsigned short*)((char*)Pl + byte) = f2bf(sc[fn][r]);
      }

    // PV: acc_o += P(16x64) @ V^T
#pragma unroll
    for (int ks = 0; ks < 2; ++ks) {
      const int arow = w * 16 + li;
      int abyte = arow * 128 + ks * 64 + g * 16;
      abyte ^= (arow & 7) << 4;
      bf8_t a = *(const bf8_t*)((const char*)Pl + abyte);
      bf8_t b[4];
#pragma unroll
      for (int fn2 = 0; fn2 < 4; ++fn2)
        b[fn2] = *chunk128(Vl, fn2 * 16 + li, ks * 4 + g);
#pragma unroll
      for (int fn2 = 0; fn2 < 4; ++fn2)
        acc_o[fn2] = __builtin_amdgcn_mfma_f32_16x16x32_bf16(a, b[fn2], acc_o[fn2], 0, 0, 0);
    }

    if (jt + 1 < 16) {
      __builtin_amdgcn_s_barrier();            // C: all waves done reading K/V
      stage(jt + 1);                            // latency covered by next Tcp phase
    }
  }

  // epilogue: normalize, write ctx [B*S, E] bf16
#pragma unroll
  for (int fn2 = 0; fn2 < 4; ++fn2)
#pragma unroll
    for (int r = 0; r < 4; ++r) {
      const int row = i0 + w * 16 + g * 4 + r;
      const int d = fn2 * 16 + li;
      float v = acc_o[fn2][r] / l_r[r];
      ctx[((long)bb * 1024 + row) * 768 + h * 64 + d] = f2bf(v);
    }
}

// ---------------- host launch ---------------------------------------------
extern "C" void kernel_launch(void* const* d_in, const int* in_sizes, int n_in,
                              void* d_out, int out_size, void* d_ws, size_t ws_size,
                              hipStream_t stream)
{
  const float* x   = (const float*)d_in[0];
  const float* Wq  = (const float*)d_in[1];
  const float* bq  = (const float*)d_in[2];
  const float* Wk  = (const float*)d_in[3];
  const float* bk  = (const float*)d_in[4];
  const float* Wv  = (const float*)d_in[5];
  const float* bv  = (const float*)d_in[6];
  const float* Wpq = (const float*)d_in[7];
  const float* bpq = (const float*)d_in[8];
  const float* Wpk = (const float*)d_in[9];
  const float* bpk = (const float*)d_in[10];
  const float* rel = (const float*)d_in[11];
  const float* Wo  = (const float*)d_in[12];
  const float* bo  = (const float*)d_in[13];

  char* ws = (char*)d_ws;
  auto alloc = [&](size_t bytes) { char* p = ws; ws += (bytes + 255) & ~(size_t)255; return p; };
  unsigned short* xb   = (unsigned short*)alloc((size_t)4096 * 768 * 2);
  unsigned short* Wqb  = (unsigned short*)alloc((size_t)768 * 768 * 2);   // contiguous Wq|Wk|Wv
  unsigned short* Wkb  = (unsigned short*)alloc((size_t)768 * 768 * 2);
  unsigned short* Wvb  = (unsigned short*)alloc((size_t)768 * 768 * 2);
  unsigned short* Wpqb = (unsigned short*)alloc((size_t)768 * 768 * 2);   // contiguous Wpq|Wpk
  unsigned short* Wpkb = (unsigned short*)alloc((size_t)768 * 768 * 2);
  unsigned short* Wob  = (unsigned short*)alloc((size_t)768 * 768 * 2);
  unsigned short* relb = (unsigned short*)alloc((size_t)1025 * 768 * 2);
  unsigned short* Qb   = (unsigned short*)alloc((size_t)48 * 1024 * 64 * 2);  // contiguous Q|K|Vt
  unsigned short* Kb   = (unsigned short*)alloc((size_t)48 * 1024 * 64 * 2);
  unsigned short* Vt   = (unsigned short*)alloc((size_t)48 * 64 * 1024 * 2);
  unsigned short* qkx  = (unsigned short*)alloc((size_t)2 * 12 * 2048 * 64 * 2); // ext qr|kr
  unsigned short* ctx  = (unsigned short*)alloc((size_t)4096 * 768 * 2);

  CvtArgs ca;
  const float* srcs[8] = {x, Wq, Wk, Wv, Wpq, Wpk, Wo, rel};
  unsigned short* dsts[8] = {xb, Wqb, Wkb, Wvb, Wpqb, Wpkb, Wob, relb};
  const int nch[8] = {786432, 147456, 147456, 147456, 147456, 147456, 147456, 196800};
  int total = 0;
  for (int i = 0; i < 8; ++i) { ca.src[i] = srcs[i]; ca.dst[i] = dsts[i]; ca.nchunks[i] = nch[i]; total += nch[i]; }
  cvt_kernel<<<dim3(2048), dim3(256), 0, stream>>>(ca, total);

  dim3 blk(256);
  // fused QKV projection: [4096,768] x [2304,768]^T -> Q|K|Vt
  gemm_bt<MQKVF><<<dim3(18, 64), blk, 0, stream>>>(xb, 768, Wqb, 768, Qb, bq, bk, bv, 4096, 2304, 768);
  // fused positional projections -> ext-table centers
  gemm_bt<MRELF><<<dim3(12, 17), blk, 0, stream>>>(relb, 768, Wpqb, 768, qkx, bpq, bpk, nullptr, 1025, 1536, 768);
  // replicate saturation rows
  expand_kernel<<<dim3(768), blk, 0, stream>>>(qkx);
  // fused scores(cc+cp+pc) + softmax + PV  (768 blocks, XCD-swizzled, 3/CU)
  flash_kernel<<<dim3(768), blk, 0, stream>>>(Qb, Kb, qkx + 1572864, qkx, Vt, ctx);
  // output projection: [4096,768] x [768,768]^T -> fp32 d_out
  gemm_bt<MOUT><<<dim3(6, 64), blk, 0, stream>>>(ctx, 768, Wob, 768, d_out, bo, nullptr, nullptr, 4096, 768, 768);

  (void)in_sizes; (void)n_in; (void)out_size; (void)ws_size;
}

// Round 9
// 220.324 us; speedup vs baseline: 1.7815x; 1.1538x over previous
//
#include <hip/hip_runtime.h>
#include <stdint.h>

typedef __attribute__((ext_vector_type(8))) short bf8_t;   // 8 x bf16 (raw bits)
typedef __attribute__((ext_vector_type(4))) float f4_t;

#define DEV __device__ __forceinline__

constexpr int S_ = 1024;
constexpr float SCALE2_ = 0.104117584f;   // 1/sqrt(192) * log2(e)

DEV float bf2f(unsigned short u) { union { unsigned int i; float f; } v; v.i = ((unsigned int)u) << 16; return v.f; }
DEV unsigned short f2bf(float f) {
  union { float fv; unsigned int i; } v; v.fv = f;
  unsigned int r = v.i + 0x7FFFu + ((v.i >> 16) & 1u);
  return (unsigned short)(r >> 16);
}

DEV void gll16(const unsigned short* g, unsigned short* l) {
  __builtin_amdgcn_global_load_lds(
      (const __attribute__((address_space(1))) unsigned int*)g,
      (__attribute__((address_space(3))) unsigned int*)l, 16, 0, 0);
}

// 128B-row LDS tile, chunk-XOR swizzled
DEV const bf8_t* chunk128(const unsigned short* base, int row, int ck) {
  return (const bf8_t*)((const char*)base + row * 128 + (((ck ^ row) & 7) << 4));
}

// ---------------- fp32 -> bf16 bulk conversion (8 tensors, one launch) ----
struct CvtArgs { const float* src[8]; unsigned short* dst[8]; int nchunks[8]; };

__global__ __launch_bounds__(256) void cvt_kernel(CvtArgs a, int total) {
  int idx = blockIdx.x * 256 + threadIdx.x;
  int step = gridDim.x * 256;
  for (; idx < total; idx += step) {
    int c = idx, s = 0;
    while (c >= a.nchunks[s]) { c -= a.nchunks[s]; ++s; }
    float4 v = ((const float4*)a.src[s])[c];
    ushort4 o;
    o.x = f2bf(v.x); o.y = f2bf(v.y); o.z = f2bf(v.z); o.w = f2bf(v.w);
    ((ushort4*)a.dst[s])[c] = o;
  }
}

// ---- bf16 GEMM: C = A * B^T (+bias), BK=64 gll16 staging, 64x128 tile ----
enum { MQKVF = 0, MRELF = 1, MOUT = 2 };

template <int MODE>
__global__ __launch_bounds__(256) void gemm_bt(
    const unsigned short* __restrict__ A, int lda,
    const unsigned short* __restrict__ B, int ldb,
    void* __restrict__ C,
    const float* __restrict__ b0, const float* __restrict__ b1, const float* __restrict__ b2,
    int M, int N, int Kd)
{
  __shared__ unsigned short At[64 * 64];    // 8KB, 128B rows, chunk-swizzled
  __shared__ unsigned short Bt[128 * 64];   // 16KB
  const int tid = threadIdx.x, lane = tid & 63, w = tid >> 6;
  const int li = lane & 15, g = lane >> 4;
  const int wr = w >> 1, wc = w & 1;
  const int m0 = blockIdx.y * 64, n0 = blockIdx.x * 128;

  // staging: chunk c -> row=c>>3, phys p=c&7, logical l = p ^ (row&7)
  const int srow = tid >> 3;
  const int sl = (tid & 7) ^ (srow & 7);
  const long aoff0 = (long)min(m0 + srow,      M - 1) * lda + sl * 8;
  const long aoff1 = (long)min(m0 + srow + 32, M - 1) * lda + sl * 8;
  const long boff0 = (long)min(n0 + srow,      N - 1) * ldb + sl * 8;
  const long boff1 = (long)min(n0 + srow + 32, N - 1) * ldb + sl * 8;
  const long boff2 = (long)min(n0 + srow + 64, N - 1) * ldb + sl * 8;
  const long boff3 = (long)min(n0 + srow + 96, N - 1) * ldb + sl * 8;

  f4_t acc[2][4];
#pragma unroll
  for (int i = 0; i < 2; ++i)
#pragma unroll
    for (int j = 0; j < 4; ++j) acc[i][j] = f4_t{0.f, 0.f, 0.f, 0.f};

  for (int k0 = 0; k0 < Kd; k0 += 64) {
    gll16(A + aoff0 + k0, At + tid * 8);
    gll16(A + aoff1 + k0, At + tid * 8 + 2048);
    gll16(B + boff0 + k0, Bt + tid * 8);
    gll16(B + boff1 + k0, Bt + tid * 8 + 2048);
    gll16(B + boff2 + k0, Bt + tid * 8 + 4096);
    gll16(B + boff3 + k0, Bt + tid * 8 + 6144);
    asm volatile("s_waitcnt vmcnt(0)" ::: "memory");
    __syncthreads();

#pragma unroll
    for (int ks = 0; ks < 2; ++ks) {
      bf8_t a[2], b[4];
#pragma unroll
      for (int fm = 0; fm < 2; ++fm)
        a[fm] = *chunk128(At, wr * 32 + fm * 16 + li, ks * 4 + g);
#pragma unroll
      for (int fn = 0; fn < 4; ++fn)
        b[fn] = *chunk128(Bt, wc * 64 + fn * 16 + li, ks * 4 + g);
#pragma unroll
      for (int fm = 0; fm < 2; ++fm)
#pragma unroll
        for (int fn = 0; fn < 4; ++fn)
          acc[fm][fn] = __builtin_amdgcn_mfma_f32_16x16x32_bf16(a[fm], b[fn], acc[fm][fn], 0, 0, 0);
    }
    __syncthreads();
  }

#pragma unroll
  for (int fm = 0; fm < 2; ++fm)
#pragma unroll
    for (int fn = 0; fn < 4; ++fn)
#pragma unroll
      for (int r = 0; r < 4; ++r) {
        int row = wr * 32 + fm * 16 + g * 4 + r;
        int col = wc * 64 + fn * 16 + li;
        int m = m0 + row, n = n0 + col;
        if (m >= M || n >= N) continue;
        float v = acc[fm][fn][r];
        if constexpr (MODE == MQKVF) {
          int sel = (n >= 1536) ? 2 : (n >= 768 ? 1 : 0);
          int nn = n - sel * 768;
          v += (sel == 0 ? b0 : sel == 1 ? b1 : b2)[nn];
          long off = (long)sel * 3145728 + (long)((m >> 10) * 12 + (nn >> 6)) * 65536;
          if (sel == 2) off += (nn & 63) * 1024 + (m & 1023);   // V transposed
          else          off += (m & 1023) * 64 + (nn & 63);
          ((unsigned short*)C)[off] = f2bf(v);
        } else if constexpr (MODE == MRELF) {
          // compact tables: [2 tbl][12 h][1025 t][64 d]
          int sel = n >= 768 ? 1 : 0;
          int nn = n - sel * 768;
          v += (sel ? b1 : b0)[nn];
          long off = (long)sel * 787200 + (long)(nn >> 6) * 65600 + (long)m * 64 + (nn & 63);
          ((unsigned short*)C)[off] = f2bf(v);
        } else {
          v += b0[n];
          ((float*)C)[(long)m * 768 + n] = v;
        }
      }
}

// ------- fused flash: cc + cp(per-wave strip) + pc + softmax + PV ---------
__global__ __launch_bounds__(256) void flash_kernel(
    const unsigned short* __restrict__ Q, const unsigned short* __restrict__ Kc,
    const unsigned short* __restrict__ kr, const unsigned short* __restrict__ qr,
    const unsigned short* __restrict__ Vt, unsigned short* __restrict__ ctx)
{
  // bijective XCD swizzle: each XCD owns 6 whole bh (all 16 i-tiles together)
  const int flat = blockIdx.x;
  const int logical = (flat & 7) * 96 + (flat >> 3);
  const int bh = logical >> 4, h = bh % 12, bb = bh / 12;
  const int i0 = (logical & 15) * 64;
  const int tid = threadIdx.x, lane = tid & 63, w = tid >> 6;
  const int g = lane >> 4, li = lane & 15;
  const unsigned short* Qb  = Q  + (long)bh * (S_ * 64);
  const unsigned short* Kb  = Kc + (long)bh * (S_ * 64);
  const unsigned short* Vb  = Vt + (long)bh * (S_ * 64);   // [64 d][1024 s]
  const unsigned short* krh = kr + (long)h * 65600;        // compact [1025][64]
  const unsigned short* qrh = qr + (long)h * 65600;

  __shared__ unsigned short Kt[4096];        // single buf, 64x64, XOR-swizzled chunks
  __shared__ unsigned short Vl[4096];        // single buf
  __shared__ unsigned short Tpc[64][132];
  __shared__ unsigned short TcpW[4][16][84]; // per-wave cp strips (42 dw/row)
  __shared__ unsigned short Pl[4096];        // per-wave P rows, XOR-swizzled

  const int mh = w & 1, nq = w >> 1;

  // stage K-tile + V-tile for tile jt (source-preswizzled, linear LDS dest)
  const int sr0 = w * 8 + (lane >> 3);
  const int scc = (lane & 7) ^ (sr0 & 7);
  auto stage = [&](int jt) {
    const int j0n = jt * 64;
    gll16(Kb + (long)(j0n + sr0) * 64 + scc * 8,        &Kt[w * 512 + lane * 8]);
    gll16(Kb + (long)(j0n + sr0 + 32) * 64 + scc * 8,   &Kt[w * 512 + 2048 + lane * 8]);
    gll16(Vb + (long)sr0 * 1024 + j0n + scc * 8,        &Vl[w * 512 + lane * 8]);
    gll16(Vb + (long)(sr0 + 32) * 1024 + j0n + scc * 8, &Vl[w * 512 + 2048 + lane * 8]);
  };

  // hoisted Q fragments: wave w owns rows i0 + w*16 .. +16
  bf8_t q3[2];
#pragma unroll
  for (int ks = 0; ks < 2; ++ks)
    q3[ks] = *(const bf8_t*)(Qb + (long)(i0 + w * 16 + li) * 64 + ks * 32 + g * 8);

  float m_r[4], l_r[4];
  f4_t acc_o[4];
#pragma unroll
  for (int r = 0; r < 4; ++r) { m_r[r] = -1e30f; l_r[r] = 0.f; }
#pragma unroll
  for (int fn = 0; fn < 4; ++fn) acc_o[fn] = f4_t{0.f, 0.f, 0.f, 0.f};

  const int base_cp = li + 15 - g * 4;          // + fn*16 - r  -> [0,78]
  const int base_pc = 63 + w * 16 + g * 4 - li; // + r - fn*16  -> [0,126]

  stage(0);

  for (int jt = 0; jt < 16; ++jt) {
    const int j0 = jt * 64;
    const int Dl = j0 - i0;
    const int wbU = Dl - w * 16 - 15 + 512;     // unclamped strip base
    const int rbU = 449 - Dl;                   // unclamped Tpc window base

    { // Tcp phase (regs + own strip; no K/V dep — covers stage latency)
      f4_t at[5];
#pragma unroll
      for (int f5 = 0; f5 < 5; ++f5) at[f5] = f4_t{0.f, 0.f, 0.f, 0.f};
#pragma unroll
      for (int ks = 0; ks < 2; ++ks) {
        bf8_t b[5];
#pragma unroll
        for (int f5 = 0; f5 < 5; ++f5) {
          int krow = min(max(wbU + f5 * 16 + li, 0), 1024);   // per-row clamp
          b[f5] = *(const bf8_t*)(krh + (long)krow * 64 + ks * 32 + g * 8);
        }
#pragma unroll
        for (int f5 = 0; f5 < 5; ++f5)
          at[f5] = __builtin_amdgcn_mfma_f32_16x16x32_bf16(q3[ks], b[f5], at[f5], 0, 0, 0);
      }
#pragma unroll
      for (int f5 = 0; f5 < 5; ++f5)
#pragma unroll
        for (int r = 0; r < 4; ++r)
          TcpW[w][g * 4 + r][f5 * 16 + li] = f2bf(at[f5][r]);
    }

    asm volatile("s_waitcnt vmcnt(0)" ::: "memory");
    __builtin_amdgcn_s_barrier();              // A: K,V staged & visible

    { // Tpc = Ktile(64x64) @ qrWin(128x64)^T
      f4_t acc[2][4];
#pragma unroll
      for (int i = 0; i < 2; ++i)
#pragma unroll
        for (int j = 0; j < 4; ++j) acc[i][j] = f4_t{0.f, 0.f, 0.f, 0.f};
#pragma unroll
      for (int ks = 0; ks < 2; ++ks) {
        bf8_t a[2], b[4];
#pragma unroll
        for (int fm = 0; fm < 2; ++fm)
          a[fm] = *chunk128(Kt, mh * 32 + fm * 16 + li, ks * 4 + g);
#pragma unroll
        for (int fn = 0; fn < 4; ++fn) {
          int qrow = min(max(rbU + nq * 64 + fn * 16 + li, 0), 1024);  // per-row clamp
          b[fn] = *(const bf8_t*)(qrh + (long)qrow * 64 + ks * 32 + g * 8);
        }
#pragma unroll
        for (int fm = 0; fm < 2; ++fm)
#pragma unroll
          for (int fn = 0; fn < 4; ++fn)
            acc[fm][fn] = __builtin_amdgcn_mfma_f32_16x16x32_bf16(a[fm], b[fn], acc[fm][fn], 0, 0, 0);
      }
#pragma unroll
      for (int fm = 0; fm < 2; ++fm)
#pragma unroll
        for (int fn = 0; fn < 4; ++fn)
#pragma unroll
          for (int r = 0; r < 4; ++r)
            Tpc[mh * 32 + fm * 16 + g * 4 + r][nq * 64 + fn * 16 + li] = f2bf(acc[fm][fn][r]);
    }

    asm volatile("s_waitcnt lgkmcnt(0)" ::: "memory");
    __builtin_amdgcn_s_barrier();              // B: Tpc visible

    // cc MFMA — wave w: rows [w*16, w*16+16), all 64 cols
    f4_t s4[4];
#pragma unroll
    for (int fn = 0; fn < 4; ++fn) s4[fn] = f4_t{0.f, 0.f, 0.f, 0.f};
#pragma unroll
    for (int ks = 0; ks < 2; ++ks) {
      bf8_t b[4];
#pragma unroll
      for (int fn = 0; fn < 4; ++fn)
        b[fn] = *chunk128(Kt, fn * 16 + li, ks * 4 + g);
#pragma unroll
      for (int fn = 0; fn < 4; ++fn)
        s4[fn] = __builtin_amdgcn_mfma_f32_16x16x32_bf16(q3[ks], b[fn], s4[fn], 0, 0, 0);
    }

    // gather cp (own strip) + pc (Tpc); affine cols (strip holds clamped rows)
    float sc[4][4];
#pragma unroll
    for (int fn = 0; fn < 4; ++fn)
#pragma unroll
      for (int r = 0; r < 4; ++r) {
        float v = s4[fn][r] + bf2f(TcpW[w][g * 4 + r][base_cp + fn * 16 - r])
                            + bf2f(Tpc[fn * 16 + li][base_pc + r - fn * 16]);
        sc[fn][r] = v * SCALE2_;
      }

    // online softmax, exp2 domain (rows replicated over 16 lanes li)
    float fac[4];
#pragma unroll
    for (int r = 0; r < 4; ++r) {
      float mx = fmaxf(fmaxf(sc[0][r], sc[1][r]), fmaxf(sc[2][r], sc[3][r]));
#pragma unroll
      for (int off = 1; off < 16; off <<= 1) mx = fmaxf(mx, __shfl_xor(mx, off));
      float mnew = fmaxf(m_r[r], mx);
      fac[r] = exp2f(m_r[r] - mnew);
      float rs = 0.f;
#pragma unroll
      for (int fn = 0; fn < 4; ++fn) { sc[fn][r] = exp2f(sc[fn][r] - mnew); rs += sc[fn][r]; }
#pragma unroll
      for (int off = 1; off < 16; off <<= 1) rs += __shfl_xor(rs, off);
      l_r[r] = l_r[r] * fac[r] + rs;
      m_r[r] = mnew;
    }
#pragma unroll
    for (int fn = 0; fn < 4; ++fn)
#pragma unroll
      for (int r = 0; r < 4; ++r) acc_o[fn][r] *= fac[r];

    // write P (bf16) to swizzled per-wave LDS
#pragma unroll
    for (int fn = 0; fn < 4; ++fn)
#pragma unroll
      for (int r = 0; r < 4; ++r) {
        const int row = w * 16 + g * 4 + r;
        int byte = row * 128 + (fn * 16 + li) * 2;
        byte ^= (row & 7) << 4;
        *(unsigned short*)((char*)Pl + byte) = f2bf(sc[fn][r]);
      }

    // PV: acc_o += P(16x64) @ V^T
#pragma unroll
    for (int ks = 0; ks < 2; ++ks) {
      const int arow = w * 16 + li;
      int abyte = arow * 128 + ks * 64 + g * 16;
      abyte ^= (arow & 7) << 4;
      bf8_t a = *(const bf8_t*)((const char*)Pl + abyte);
      bf8_t b[4];
#pragma unroll
      for (int fn2 = 0; fn2 < 4; ++fn2)
        b[fn2] = *chunk128(Vl, fn2 * 16 + li, ks * 4 + g);
#pragma unroll
      for (int fn2 = 0; fn2 < 4; ++fn2)
        acc_o[fn2] = __builtin_amdgcn_mfma_f32_16x16x32_bf16(a, b[fn2], acc_o[fn2], 0, 0, 0);
    }

    if (jt + 1 < 16) {
      __builtin_amdgcn_s_barrier();            // C: all waves done reading K/V
      stage(jt + 1);                            // latency covered by next Tcp phase
    }
  }

  // epilogue: normalize, write ctx [B*S, E] bf16
#pragma unroll
  for (int fn2 = 0; fn2 < 4; ++fn2)
#pragma unroll
    for (int r = 0; r < 4; ++r) {
      const int row = i0 + w * 16 + g * 4 + r;
      const int d = fn2 * 16 + li;
      float v = acc_o[fn2][r] / l_r[r];
      ctx[((long)bb * 1024 + row) * 768 + h * 64 + d] = f2bf(v);
    }
}

// ---------------- host launch ---------------------------------------------
extern "C" void kernel_launch(void* const* d_in, const int* in_sizes, int n_in,
                              void* d_out, int out_size, void* d_ws, size_t ws_size,
                              hipStream_t stream)
{
  const float* x   = (const float*)d_in[0];
  const float* Wq  = (const float*)d_in[1];
  const float* bq  = (const float*)d_in[2];
  const float* Wk  = (const float*)d_in[3];
  const float* bk  = (const float*)d_in[4];
  const float* Wv  = (const float*)d_in[5];
  const float* bv  = (const float*)d_in[6];
  const float* Wpq = (const float*)d_in[7];
  const float* bpq = (const float*)d_in[8];
  const float* Wpk = (const float*)d_in[9];
  const float* bpk = (const float*)d_in[10];
  const float* rel = (const float*)d_in[11];
  const float* Wo  = (const float*)d_in[12];
  const float* bo  = (const float*)d_in[13];

  char* ws = (char*)d_ws;
  auto alloc = [&](size_t bytes) { char* p = ws; ws += (bytes + 255) & ~(size_t)255; return p; };
  unsigned short* xb   = (unsigned short*)alloc((size_t)4096 * 768 * 2);
  unsigned short* Wqb  = (unsigned short*)alloc((size_t)768 * 768 * 2);   // contiguous Wq|Wk|Wv
  unsigned short* Wkb  = (unsigned short*)alloc((size_t)768 * 768 * 2);
  unsigned short* Wvb  = (unsigned short*)alloc((size_t)768 * 768 * 2);
  unsigned short* Wpqb = (unsigned short*)alloc((size_t)768 * 768 * 2);   // contiguous Wpq|Wpk
  unsigned short* Wpkb = (unsigned short*)alloc((size_t)768 * 768 * 2);
  unsigned short* Wob  = (unsigned short*)alloc((size_t)768 * 768 * 2);
  unsigned short* relb = (unsigned short*)alloc((size_t)1025 * 768 * 2);
  unsigned short* Qb   = (unsigned short*)alloc((size_t)48 * 1024 * 64 * 2);  // contiguous Q|K|Vt
  unsigned short* Kb   = (unsigned short*)alloc((size_t)48 * 1024 * 64 * 2);
  unsigned short* Vt   = (unsigned short*)alloc((size_t)48 * 64 * 1024 * 2);
  unsigned short* qkx  = (unsigned short*)alloc((size_t)2 * 12 * 1025 * 64 * 2); // compact qr|kr
  unsigned short* ctx  = (unsigned short*)alloc((size_t)4096 * 768 * 2);

  CvtArgs ca;
  const float* srcs[8] = {x, Wq, Wk, Wv, Wpq, Wpk, Wo, rel};
  unsigned short* dsts[8] = {xb, Wqb, Wkb, Wvb, Wpqb, Wpkb, Wob, relb};
  const int nch[8] = {786432, 147456, 147456, 147456, 147456, 147456, 147456, 196800};
  int total = 0;
  for (int i = 0; i < 8; ++i) { ca.src[i] = srcs[i]; ca.dst[i] = dsts[i]; ca.nchunks[i] = nch[i]; total += nch[i]; }
  cvt_kernel<<<dim3(2048), dim3(256), 0, stream>>>(ca, total);

  dim3 blk(256);
  // fused QKV projection: [4096,768] x [2304,768]^T -> Q|K|Vt
  gemm_bt<MQKVF><<<dim3(18, 64), blk, 0, stream>>>(xb, 768, Wqb, 768, Qb, bq, bk, bv, 4096, 2304, 768);
  // fused positional projections -> compact tables [2][12][1025][64]
  gemm_bt<MRELF><<<dim3(12, 17), blk, 0, stream>>>(relb, 768, Wpqb, 768, qkx, bpq, bpk, nullptr, 1025, 1536, 768);
  // fused scores(cc+cp+pc) + softmax + PV  (768 blocks, XCD-swizzled, 3/CU)
  flash_kernel<<<dim3(768), blk, 0, stream>>>(Qb, Kb, qkx + 787200, qkx, Vt, ctx);
  // output projection: [4096,768] x [768,768]^T -> fp32 d_out
  gemm_bt<MOUT><<<dim3(6, 64), blk, 0, stream>>>(ctx, 768, Wob, 768, d_out, bo, nullptr, nullptr, 4096, 768, 768);

  (void)in_sizes; (void)n_in; (void)out_size; (void)ws_size;
}